// Round 9
// baseline (591.577 us; speedup 1.0000x reference)
//
#include <hip/hip_runtime.h>
#include <hip/hip_bf16.h>
#include <math.h>

#define BB 8
#define NN 2048
#define DD 128
#define SPL 8       // K-split for the 128x128 TN MFMA GEMMs
#define CAPH 16     // per (col, quarter) capacity within one i-half

typedef __bf16 bf16x8 __attribute__((ext_vector_type(8)));
typedef float f32x4 __attribute__((ext_vector_type(4)));

__device__ inline unsigned short f2bu(float f) {
  __hip_bfloat16 h = __float2bfloat16(f);
  return *reinterpret_cast<unsigned short*>(&h);
}
__device__ inline unsigned int pack2(float a, float b) {
  return (unsigned int)f2bu(a) | ((unsigned int)f2bu(b) << 16);
}
__device__ inline float blo(unsigned u) { return __uint_as_float(u << 16); }
__device__ inline float bhi(unsigned u) { return __uint_as_float(u & 0xffff0000u); }

// Half-range pass over adj (z picks i-half): per-column 32-slot index segment,
// per-half count, per-block nnz partial. z==0 blocks also convert x to bf16.
__global__ __launch_bounds__(256) void k_build(const float* __restrict__ adj,
                                               const float* __restrict__ x,
                                               unsigned short* __restrict__ colidx,
                                               float* __restrict__ cnth,     // [2][B*NN]
                                               float* __restrict__ nnzpart,  // [512]
                                               __hip_bfloat16* __restrict__ xb,
                                               unsigned* __restrict__ counter) {
  __shared__ float T[2][64][65];
  __shared__ unsigned short L[64][4][CAPH];
  __shared__ int cnts[64][4];
  __shared__ float tsum[64];
  int b = blockIdx.y, j0 = blockIdx.x * 64, z = blockIdx.z;
  int linear = (z * 8 + blockIdx.y) * 32 + blockIdx.x;
  if (linear == 0 && threadIdx.x == 0) *counter = 0;
  const float* A = adj + (size_t)b * NN * NN + (size_t)z * 1024 * NN + j0;
  int t = threadIdx.x;
  int lr = t >> 2, lc0 = (t & 3) * 16;
  int sc = t & 63, sq = t >> 6;
  float4 pre[4];
  #pragma unroll
  for (int e = 0; e < 4; ++e)
    pre[e] = *(const float4*)(A + (size_t)lr * NN + lc0 + e * 4);
  #pragma unroll
  for (int e = 0; e < 4; ++e)
    *(float4*)&T[0][lr][lc0 + e * 4] = pre[e];
  __syncthreads();
  int cnt = 0;
  for (int ch = 0; ch < 16; ++ch) {
    if (ch + 1 < 16) {
      const float* src = A + (size_t)(ch + 1) * 64 * NN;
      #pragma unroll
      for (int e = 0; e < 4; ++e)
        pre[e] = *(const float4*)(src + (size_t)lr * NN + lc0 + e * 4);
    }
    #pragma unroll
    for (int p = 0; p < 16; ++p) {
      int il = sq * 16 + p;
      float v = T[ch & 1][il][sc];
      if (v != 0.f) {
        L[sc][sq][cnt < CAPH ? cnt : CAPH - 1] = (unsigned short)(z * 1024 + ch * 64 + il);
        ++cnt;
      }
    }
    if (ch + 1 < 16) {
      #pragma unroll
      for (int e = 0; e < 4; ++e)
        *(float4*)&T[(ch + 1) & 1][lr][lc0 + e * 4] = pre[e];
    }
    __syncthreads();
  }
  cnts[sc][sq] = cnt;
  __syncthreads();
  int c = t >> 2, seg = t & 3;
  int n0 = cnts[c][0], n1 = cnts[c][1], n2 = cnts[c][2], n3 = cnts[c][3];
  int tot = n0 + n1 + n2 + n3;
  unsigned short vals[8];
  #pragma unroll
  for (int e = 0; e < 8; ++e) {
    int k = seg * 8 + e;
    unsigned short xv = 0;
    if (k < n0) xv = L[c][0][k];
    else if (k < n0 + n1) xv = L[c][1][k - n0];
    else if (k < n0 + n1 + n2) xv = L[c][2][k - n0 - n1];
    else if (k < tot) xv = L[c][3][k - n0 - n1 - n2];
    vals[e] = xv;
  }
  size_t jg = (size_t)b * NN + j0 + c;
  *(uint4*)(colidx + jg * 64 + z * 32 + seg * 8) = *(uint4*)vals;
  if (seg == 0) {
    cnth[(size_t)z * (BB * NN) + jg] = (float)tot;
    tsum[c] = (float)tot;
  }
  __syncthreads();
  if (t < 64) {
    float s = tsum[t];
    #pragma unroll
    for (int off = 32; off > 0; off >>= 1) s += __shfl_xor(s, off);
    if (t == 0) nnzpart[linear] = s;
  }
  if (z == 0) {
    size_t base = (size_t)(blockIdx.y * 32 + blockIdx.x) * 8192;
    #pragma unroll
    for (int e = 0; e < 8; ++e) {
      size_t off = base + e * 1024 + t * 4;
      float4 a = *(const float4*)(x + off);
      unsigned r2[2] = {pack2(a.x, a.y), pack2(a.z, a.w)};
      *(uint2*)((unsigned short*)xb + off) = *(uint2*)r2;
    }
  }
}

// wave-cooperative gather of columns jA,jB aggregation (lane l covers d=2l,2l+1)
__device__ __forceinline__ void gather2(const unsigned short* __restrict__ Vb,
                                        const unsigned short* __restrict__ colidx,
                                        const float* __restrict__ cnth,
                                        size_t gA, size_t gB, int l,
                                        unsigned& pa, unsigned& pb) {
  int a0 = min((int)cnth[gA], 32), a1 = min((int)cnth[(size_t)BB * NN + gA], 32);
  int b0 = min((int)cnth[gB], 32), b1 = min((int)cnth[(size_t)BB * NN + gB], 32);
  float scA = 1.f / fmaxf((float)(a0 + a1), 1.f);
  float scB = 1.f / fmaxf((float)(b0 + b1), 1.f);
  int miA = colidx[gA * 64 + l];
  int miB = colidx[gB * 64 + l];
  float axA = 0.f, ayA = 0.f, axB = 0.f, ayB = 0.f;
  #pragma unroll
  for (int sgm = 0; sgm < 2; ++sgm) {
    int ccA = sgm ? a1 : a0;
    int ccB = sgm ? b1 : b0;
    int lb = sgm ? 32 : 0;
    int km = max(ccA, ccB);
    for (int k = 0; k < km; k += 2) {
      if (k < ccA) {
        unsigned u = *(const unsigned*)(Vb + (size_t)__shfl(miA, lb + k) * DD + 2 * l);
        axA += blo(u); ayA += bhi(u);
      }
      if (k + 1 < ccA) {
        unsigned u = *(const unsigned*)(Vb + (size_t)__shfl(miA, lb + k + 1) * DD + 2 * l);
        axA += blo(u); ayA += bhi(u);
      }
      if (k < ccB) {
        unsigned u = *(const unsigned*)(Vb + (size_t)__shfl(miB, lb + k) * DD + 2 * l);
        axB += blo(u); ayB += bhi(u);
      }
      if (k + 1 < ccB) {
        unsigned u = *(const unsigned*)(Vb + (size_t)__shfl(miB, lb + k + 1) * DD + 2 * l);
        axB += blo(u); ayB += bhi(u);
      }
    }
  }
  pa = pack2(axA * scA, ayA * scA);
  pb = pack2(axB * scB, ayB * scB);
}

// Round-1 dual linred with FUSED aggregation gather: V = xbf serves as both
// gather source (agg) and skip input (X2). Computes both weight sets.
__global__ __launch_bounds__(256) void k_lin2(const __hip_bfloat16* __restrict__ V,
                                              const unsigned short* __restrict__ colidx,
                                              const float* __restrict__ cnth,
                                              const float* __restrict__ W0a,
                                              const float* __restrict__ W0b,
                                              const float* __restrict__ b0,
                                              const float* __restrict__ W1a,
                                              const float* __restrict__ W1b,
                                              const float* __restrict__ b1,
                                              __hip_bfloat16* __restrict__ out0,
                                              __hip_bfloat16* __restrict__ out1) {
  __shared__ __align__(16) char smem[64 * 136 * 2 * 2];
  __shared__ __align__(16) __hip_bfloat16 Wsm[2][128 * 72];
  __shared__ float bsm[2][128];
  __hip_bfloat16* As = (__hip_bfloat16*)smem;
  __hip_bfloat16* Xs = As + 64 * 136;
  float* Ho = (float*)smem;

  int b = blockIdx.y, j0 = blockIdx.x * 64;
  int t = threadIdx.x;
  size_t rowbase = (size_t)b * NN + j0;

  if (t < 128) { bsm[0][t] = b0[t]; bsm[1][t] = b1[t]; }
  // stage X2 rows (coalesced, loads go in flight first)
  #pragma unroll
  for (int e = 0; e < 8; ++e) {
    int idx = t + e * 256;
    int r = idx >> 5, c4 = idx & 31;
    size_t g = (rowbase + r) * DD + c4 * 4;
    *(uint2*)&Xs[r * 136 + c4 * 4] = *(const uint2*)((const unsigned short*)V + g);
  }
  // fused gather: wave w covers columns w*16 .. w*16+15
  int w = t >> 6, l = t & 63;
  const unsigned short* Vb = (const unsigned short*)V + (((size_t)b << 11)) * DD;
  for (int cc = 0; cc < 16; cc += 2) {
    int jA = w * 16 + cc;
    unsigned pa, pb;
    gather2(Vb, colidx, cnth, rowbase + jA, rowbase + jA + 1, l, pa, pb);
    *(unsigned*)&As[jA * 136 + 2 * l] = pa;
    *(unsigned*)&As[(jA + 1) * 136 + 2 * l] = pb;
  }
  __syncthreads();

  int lm = l & 15, lq = l >> 4;
  int jloc = w * 16 + lm;
  f32x4 acc0[8], acc1[8];
  #pragma unroll
  for (int mt = 0; mt < 8; ++mt)
    #pragma unroll
    for (int r = 0; r < 4; ++r) { acc0[mt][r] = 0.f; acc1[mt][r] = 0.f; }

  #pragma unroll
  for (int ph = 0; ph < 2; ++ph) {
    const __hip_bfloat16* Xt = ph ? Xs : As;
    const float* Wx = ph ? W0b : W0a;
    const float* Wy = ph ? W1b : W1a;
    #pragma unroll
    for (int ch = 0; ch < 2; ++ch) {
      __syncthreads();
      #pragma unroll
      for (int e = 0; e < 8; ++e) {
        int idx = t + e * 256;
        int o = idx >> 4, k4 = idx & 15;
        float4 wv = *(const float4*)(Wx + o * DD + ch * 64 + k4 * 4);
        uint2 pw; pw.x = pack2(wv.x, wv.y); pw.y = pack2(wv.z, wv.w);
        *(uint2*)&Wsm[0][o * 72 + k4 * 4] = pw;
        float4 wv2 = *(const float4*)(Wy + o * DD + ch * 64 + k4 * 4);
        uint2 pw2; pw2.x = pack2(wv2.x, wv2.y); pw2.y = pack2(wv2.z, wv2.w);
        *(uint2*)&Wsm[1][o * 72 + k4 * 4] = pw2;
      }
      __syncthreads();
      #pragma unroll
      for (int s = 0; s < 2; ++s) {
        int kx = ch * 64 + s * 32 + lq * 8;
        bf16x8 bfr = *(const bf16x8*)&Xt[jloc * 136 + kx];
        int kw = s * 32 + lq * 8;
        #pragma unroll
        for (int mt = 0; mt < 8; ++mt) {
          bf16x8 a0 = *(const bf16x8*)&Wsm[0][(mt * 16 + lm) * 72 + kw];
          acc0[mt] = __builtin_amdgcn_mfma_f32_16x16x32_bf16(a0, bfr, acc0[mt], 0, 0, 0);
          bf16x8 a1 = *(const bf16x8*)&Wsm[1][(mt * 16 + lm) * 72 + kw];
          acc1[mt] = __builtin_amdgcn_mfma_f32_16x16x32_bf16(a1, bfr, acc1[mt], 0, 0, 0);
        }
      }
    }
  }

  #pragma unroll
  for (int set = 0; set < 2; ++set) {
    __syncthreads();
    f32x4* acc = set ? acc1 : acc0;
    float psum = 0.f;
    float hv[8][4];
    #pragma unroll
    for (int mt = 0; mt < 8; ++mt)
      #pragma unroll
      for (int r = 0; r < 4; ++r) {
        int o = mt * 16 + lq * 4 + r;
        float v = fmaxf(acc[mt][r] + bsm[set][o], 0.f);
        hv[mt][r] = v;
        psum += v * v;
      }
    psum += __shfl_xor(psum, 16);
    psum += __shfl_xor(psum, 32);
    float rn = 1.f / (sqrtf(psum) + 1e-9f);
    #pragma unroll
    for (int mt = 0; mt < 8; ++mt)
      #pragma unroll
      for (int r = 0; r < 4; ++r) {
        int o = mt * 16 + lq * 4 + r;
        Ho[jloc * 132 + o] = hv[mt][r] * rn;
      }
    __syncthreads();
    __hip_bfloat16* ob = set ? out1 : out0;
    #pragma unroll
    for (int e = 0; e < 4; ++e) {
      int idx = t + e * 256;
      int r = idx >> 4, c8 = idx & 15;
      const float* h = &Ho[r * 132 + c8 * 8];
      unsigned pk[4] = {pack2(h[0], h[1]), pack2(h[2], h[3]),
                        pack2(h[4], h[5]), pack2(h[6], h[7])};
      *(uint4*)((unsigned short*)ob + (rowbase + r) * DD + c8 * 8) = *(uint4*)pk;
    }
  }
}

// Round-2 merged linred with FUSED gather. z=0: V=a1bf, softmax epilogue
// (Sbf, STt, entropy). z=1: V=h1bf, l2norm epilogue, transposed h2T out.
__global__ __launch_bounds__(256) void k_linz(const __hip_bfloat16* __restrict__ V0,
                                              const float* __restrict__ W0a,
                                              const float* __restrict__ W0b,
                                              const float* __restrict__ b0,
                                              __hip_bfloat16* __restrict__ Sbf,
                                              __hip_bfloat16* __restrict__ STt,
                                              float* __restrict__ entpart,
                                              const __hip_bfloat16* __restrict__ V1,
                                              const float* __restrict__ W1a,
                                              const float* __restrict__ W1b,
                                              const float* __restrict__ b1,
                                              __hip_bfloat16* __restrict__ out1T,
                                              const unsigned short* __restrict__ colidx,
                                              const float* __restrict__ cnth) {
  __shared__ __align__(16) char smem[64 * 136 * 2 * 2];
  __shared__ __align__(16) __hip_bfloat16 Wsm[128 * 72];
  __shared__ float bsm[128];
  __shared__ float entred[64];
  __hip_bfloat16* As = (__hip_bfloat16*)smem;
  __hip_bfloat16* Xs = As + 64 * 136;
  float* Ho = (float*)smem;

  int mode = blockIdx.z;
  const __hip_bfloat16* V = mode ? V1 : V0;
  const float* Wl = mode ? W1a : W0a;
  const float* Wr = mode ? W1b : W0b;
  const float* bias = mode ? b1 : b0;

  int b = blockIdx.y, j0 = blockIdx.x * 64;
  int t = threadIdx.x;
  size_t rowbase = (size_t)b * NN + j0;

  if (t < 128) bsm[t] = bias[t];
  #pragma unroll
  for (int e = 0; e < 8; ++e) {
    int idx = t + e * 256;
    int r = idx >> 5, c4 = idx & 31;
    size_t g = (rowbase + r) * DD + c4 * 4;
    *(uint2*)&Xs[r * 136 + c4 * 4] = *(const uint2*)((const unsigned short*)V + g);
  }
  int w = t >> 6, l = t & 63;
  const unsigned short* Vb = (const unsigned short*)V + (((size_t)b << 11)) * DD;
  for (int cc = 0; cc < 16; cc += 2) {
    int jA = w * 16 + cc;
    unsigned pa, pb;
    gather2(Vb, colidx, cnth, rowbase + jA, rowbase + jA + 1, l, pa, pb);
    *(unsigned*)&As[jA * 136 + 2 * l] = pa;
    *(unsigned*)&As[(jA + 1) * 136 + 2 * l] = pb;
  }
  __syncthreads();

  int lm = l & 15, lq = l >> 4;
  int jloc = w * 16 + lm;
  f32x4 acc[8];
  #pragma unroll
  for (int mt = 0; mt < 8; ++mt)
    #pragma unroll
    for (int r = 0; r < 4; ++r) acc[mt][r] = 0.f;

  #pragma unroll
  for (int ph = 0; ph < 2; ++ph) {
    const __hip_bfloat16* Xt = ph ? Xs : As;
    const float* W = ph ? Wr : Wl;
    #pragma unroll
    for (int ch = 0; ch < 2; ++ch) {
      __syncthreads();
      #pragma unroll
      for (int e = 0; e < 8; ++e) {
        int idx = t + e * 256;
        int o = idx >> 4, k4 = idx & 15;
        float4 wv = *(const float4*)(W + o * DD + ch * 64 + k4 * 4);
        uint2 pw; pw.x = pack2(wv.x, wv.y); pw.y = pack2(wv.z, wv.w);
        *(uint2*)&Wsm[o * 72 + k4 * 4] = pw;
      }
      __syncthreads();
      #pragma unroll
      for (int s = 0; s < 2; ++s) {
        int kx = ch * 64 + s * 32 + lq * 8;
        bf16x8 bfr = *(const bf16x8*)&Xt[jloc * 136 + kx];
        int kw = s * 32 + lq * 8;
        #pragma unroll
        for (int mt = 0; mt < 8; ++mt) {
          bf16x8 afr = *(const bf16x8*)&Wsm[(mt * 16 + lm) * 72 + kw];
          acc[mt] = __builtin_amdgcn_mfma_f32_16x16x32_bf16(afr, bfr, acc[mt], 0, 0, 0);
        }
      }
    }
  }

  __syncthreads();
  float hv[8][4];
  float psum = 0.f;
  #pragma unroll
  for (int mt = 0; mt < 8; ++mt)
    #pragma unroll
    for (int r = 0; r < 4; ++r) {
      int o = mt * 16 + lq * 4 + r;
      float v = fmaxf(acc[mt][r] + bsm[o], 0.f);
      hv[mt][r] = v;
      psum += v * v;
    }
  psum += __shfl_xor(psum, 16);
  psum += __shfl_xor(psum, 32);
  float rn = 1.f / (sqrtf(psum) + 1e-9f);

  if (mode == 0) {
    float av[8][4];
    float m = -3.4e38f;
    #pragma unroll
    for (int mt = 0; mt < 8; ++mt)
      #pragma unroll
      for (int r = 0; r < 4; ++r) {
        float a = hv[mt][r] * rn;
        av[mt][r] = a;
        m = fmaxf(m, a);
      }
    m = fmaxf(m, __shfl_xor(m, 16));
    m = fmaxf(m, __shfl_xor(m, 32));
    float sum = 0.f;
    #pragma unroll
    for (int mt = 0; mt < 8; ++mt)
      #pragma unroll
      for (int r = 0; r < 4; ++r) {
        float e = expf(av[mt][r] - m);
        av[mt][r] = e;
        sum += e;
      }
    sum += __shfl_xor(sum, 16);
    sum += __shfl_xor(sum, 32);
    float inv = 1.f / sum;
    float ent = 0.f;
    #pragma unroll
    for (int mt = 0; mt < 8; ++mt)
      #pragma unroll
      for (int r = 0; r < 4; ++r) {
        float p = av[mt][r] * inv;
        ent -= p * logf(p + 1e-15f);
        int o = mt * 16 + lq * 4 + r;
        Ho[jloc * 132 + o] = p;
      }
    ent += __shfl_xor(ent, 16);
    ent += __shfl_xor(ent, 32);
    if (l < 16) entred[w * 16 + lm] = ent;
    __syncthreads();
    #pragma unroll
    for (int e = 0; e < 4; ++e) {
      int idx = t + e * 256;
      int r = idx >> 4, c8 = idx & 15;
      const float* h = &Ho[r * 132 + c8 * 8];
      unsigned pk[4] = {pack2(h[0], h[1]), pack2(h[2], h[3]),
                        pack2(h[4], h[5]), pack2(h[6], h[7])};
      *(uint4*)((unsigned short*)Sbf + (rowbase + r) * DD + c8 * 8) = *(uint4*)pk;
    }
    {
      int d = t >> 1, half = t & 1;
      unsigned wv[16];
      #pragma unroll
      for (int e = 0; e < 16; ++e)
        wv[e] = pack2(Ho[(half * 32 + 2 * e) * 132 + d], Ho[(half * 32 + 2 * e + 1) * 132 + d]);
      unsigned short* dst = (unsigned short*)STt + ((size_t)b * DD + d) * NN + j0 + half * 32;
      #pragma unroll
      for (int q = 0; q < 4; ++q)
        *(uint4*)(dst + q * 8) = *(uint4*)&wv[q * 4];
    }
    if (t < 64) {
      float s = entred[t];
      #pragma unroll
      for (int off = 32; off > 0; off >>= 1) s += __shfl_xor(s, off);
      if (t == 0) entpart[blockIdx.y * 32 + blockIdx.x] = s;
    }
  } else {
    #pragma unroll
    for (int mt = 0; mt < 8; ++mt)
      #pragma unroll
      for (int r = 0; r < 4; ++r) {
        int o = mt * 16 + lq * 4 + r;
        Ho[jloc * 132 + o] = hv[mt][r] * rn;
      }
    __syncthreads();
    int d = t >> 1, half = t & 1;
    unsigned wv[16];
    #pragma unroll
    for (int e = 0; e < 16; ++e)
      wv[e] = pack2(Ho[(half * 32 + 2 * e) * 132 + d], Ho[(half * 32 + 2 * e + 1) * 132 + d]);
    unsigned short* dst = (unsigned short*)out1T + ((size_t)b * DD + d) * NN + j0 + half * 32;
    #pragma unroll
    for (int q = 0; q < 4; ++q)
      *(uint4*)(dst + q * 8) = *(uint4*)&wv[q * 4];
  }
}

// P = A^T S (unscaled), emitted TRANSPOSED: PT[b][d][t] bf16. 16 cols per block.
__global__ __launch_bounds__(256) void k_aggT(const __hip_bfloat16* __restrict__ Sbf,
                                              const unsigned short* __restrict__ colidx,
                                              const float* __restrict__ cnth,
                                              __hip_bfloat16* __restrict__ PT) {
  __shared__ float Lt[128][17];
  int w = threadIdx.x >> 6, l = threadIdx.x & 63;
  size_t jbase = (size_t)blockIdx.x * 16;
  int b = (int)(jbase >> 11);
  const unsigned short* Vb = (const unsigned short*)Sbf + (((size_t)b << 11)) * DD;
  #pragma unroll
  for (int cc4 = 0; cc4 < 4; ++cc4) {
    int jl = w * 4 + cc4;
    size_t jg = jbase + jl;
    int c0 = min((int)cnth[jg], 32);
    int c1 = min((int)cnth[(size_t)BB * NN + jg], 32);
    int myi = colidx[jg * 64 + l];
    float ax = 0.f, ay = 0.f;
    #pragma unroll
    for (int sgm = 0; sgm < 2; ++sgm) {
      int cc = sgm ? c1 : c0;
      int lb = sgm ? 32 : 0;
      int k = 0;
      for (; k + 4 <= cc; k += 4) {
        int i0 = __shfl(myi, lb + k), i1 = __shfl(myi, lb + k + 1);
        int i2 = __shfl(myi, lb + k + 2), i3 = __shfl(myi, lb + k + 3);
        unsigned u0 = *(const unsigned*)(Vb + (size_t)i0 * DD + 2 * l);
        unsigned u1 = *(const unsigned*)(Vb + (size_t)i1 * DD + 2 * l);
        unsigned u2 = *(const unsigned*)(Vb + (size_t)i2 * DD + 2 * l);
        unsigned u3 = *(const unsigned*)(Vb + (size_t)i3 * DD + 2 * l);
        ax += blo(u0) + blo(u1) + blo(u2) + blo(u3);
        ay += bhi(u0) + bhi(u1) + bhi(u2) + bhi(u3);
      }
      for (; k < cc; ++k) {
        int i0 = __shfl(myi, lb + k);
        unsigned u0 = *(const unsigned*)(Vb + (size_t)i0 * DD + 2 * l);
        ax += blo(u0); ay += bhi(u0);
      }
    }
    Lt[2 * l][jl] = ax;
    Lt[2 * l + 1][jl] = ay;
  }
  __syncthreads();
  int t = threadIdx.x;
  if (t < 128) {
    int j0 = (int)(jbase & (NN - 1));
    unsigned wv[8];
    #pragma unroll
    for (int e = 0; e < 8; ++e)
      wv[e] = pack2(Lt[t][2 * e], Lt[t][2 * e + 1]);
    unsigned short* dst = (unsigned short*)PT + ((size_t)b * DD + t) * NN + j0;
    *(uint4*)dst = *(uint4*)&wv[0];
    *(uint4*)(dst + 8) = *(uint4*)&wv[4];
  }
}

// TN MFMA: pair0 ST·h2T^T (h_pooled), pair1 PT·ST^T (adj_pooled), pair2 ST·ST^T (G)
__global__ __launch_bounds__(256) void k_tnm(const __hip_bfloat16* __restrict__ ST,
                                             const __hip_bfloat16* __restrict__ HT,
                                             const __hip_bfloat16* __restrict__ PT,
                                             float* __restrict__ part) {
  __shared__ __align__(16) __hip_bfloat16 As[128 * 64];
  __shared__ __align__(16) __hip_bfloat16 Bs[128 * 64];
  int pb = blockIdx.y;
  int pair = pb >> 3, b = pb & 7;
  const __hip_bfloat16* Xa = (pair == 1) ? PT : ST;
  const __hip_bfloat16* Ya = (pair == 0) ? HT : ST;
  const __hip_bfloat16* Ab = Xa + (size_t)b * DD * NN;
  const __hip_bfloat16* Bb = Ya + (size_t)b * DD * NN;
  int k0 = blockIdx.x * (NN / SPL);
  int tid = threadIdx.x;
  int w = tid >> 6, l = tid & 63;
  int wj = w & 1, wd = w >> 1;
  int sr = l >> 3, ss = l & 7;
  int lm = l & 15, lq = l >> 4;
  f32x4 acc[4][4];
  #pragma unroll
  for (int a = 0; a < 4; ++a)
    #pragma unroll
    for (int c = 0; c < 4; ++c)
      #pragma unroll
      for (int r = 0; r < 4; ++r) acc[a][c][r] = 0.f;

  for (int kb = 0; kb < (NN / SPL) / 64; ++kb) {
    int kbase = k0 + kb * 64;
    __syncthreads();
    #pragma unroll
    for (int e = 0; e < 4; ++e) {
      int r = 32 * w + 8 * e + sr;
      int g = ss ^ (r & 7);
      const __hip_bfloat16* srcA = Ab + (size_t)r * NN + kbase + g * 8;
      __builtin_amdgcn_global_load_lds(
          (const __attribute__((address_space(1))) void*)srcA,
          (__attribute__((address_space(3))) void*)&As[(32 * w + 8 * e) * 64], 16, 0, 0);
      const __hip_bfloat16* srcB = Bb + (size_t)r * NN + kbase + g * 8;
      __builtin_amdgcn_global_load_lds(
          (const __attribute__((address_space(1))) void*)srcB,
          (__attribute__((address_space(3))) void*)&Bs[(32 * w + 8 * e) * 64], 16, 0, 0);
    }
    __syncthreads();
    #pragma unroll
    for (int ks = 0; ks < 2; ++ks) {
      bf16x8 afr[4], bfr[4];
      int kg = ks * 4 + lq;
      #pragma unroll
      for (int jt = 0; jt < 4; ++jt) {
        int jl = wj * 64 + jt * 16 + lm;
        afr[jt] = *(const bf16x8*)&As[jl * 64 + ((kg ^ (jl & 7)) << 3)];
      }
      #pragma unroll
      for (int dt = 0; dt < 4; ++dt) {
        int dl = wd * 64 + dt * 16 + lm;
        bfr[dt] = *(const bf16x8*)&Bs[dl * 64 + ((kg ^ (dl & 7)) << 3)];
      }
      #pragma unroll
      for (int jt = 0; jt < 4; ++jt)
        #pragma unroll
        for (int dt = 0; dt < 4; ++dt)
          acc[jt][dt] = __builtin_amdgcn_mfma_f32_16x16x32_bf16(afr[jt], bfr[dt], acc[jt][dt], 0, 0, 0);
    }
  }
  float* P = part + ((size_t)(pair * SPL + blockIdx.x) * BB + b) * DD * DD;
  #pragma unroll
  for (int jt = 0; jt < 4; ++jt)
    #pragma unroll
    for (int reg = 0; reg < 4; ++reg) {
      int j = wj * 64 + jt * 16 + lq * 4 + reg;
      float* row = P + (size_t)j * DD;
      #pragma unroll
      for (int dt = 0; dt < 4; ++dt)
        row[wd * 64 + dt * 16 + lm] = acc[jt][dt][reg];
    }
}

// reduce SPL partials; last finishing block computes the two loss scalars.
__global__ __launch_bounds__(256) void k_tnred_final(const float* __restrict__ part,
                                                     float* __restrict__ out,
                                                     float* __restrict__ trpart,
                                                     float* __restrict__ sqpart,
                                                     const float* __restrict__ nnzpart,
                                                     const float* __restrict__ entpart,
                                                     unsigned* __restrict__ counter) {
  __shared__ float red[256];
  int pair = blockIdx.y;
  size_t i = (size_t)blockIdx.x * 256 + threadIdx.x;     // < B*D*D = 131072
  float s = 0.f;
  #pragma unroll
  for (int ks = 0; ks < SPL; ++ks)
    s += part[((size_t)pair * SPL + ks) * (BB * DD * DD) + i];
  float contrib = 0.f;
  if (pair == 0) {
    out[i] = s;
  } else if (pair == 1) {
    out[(size_t)BB * DD * DD + i] = s;
    int rc = (int)(i & (DD * DD - 1));
    if ((rc >> 7) == (rc & 127)) contrib = s;
  } else {
    contrib = s * s;
  }
  red[threadIdx.x] = contrib;
  __syncthreads();
  for (int off = 128; off > 0; off >>= 1) {
    if (threadIdx.x < off) red[threadIdx.x] += red[threadIdx.x + off];
    __syncthreads();
  }
  if (threadIdx.x == 0) {
    if (pair == 1) trpart[blockIdx.x] = red[0];
    else if (pair == 2) sqpart[blockIdx.x] = red[0];
  }
  __threadfence();
  __shared__ unsigned last;
  if (threadIdx.x == 0) last = atomicAdd(counter, 1u);
  __syncthreads();
  if (last == 3 * 512 - 1) {
    __threadfence();
    int t = threadIdx.x;
    float4 v;
    v.x = nnzpart[t] + nnzpart[t + 256];
    v.y = entpart[t];
    v.z = trpart[t] + trpart[t + 256];
    v.w = sqpart[t] + sqpart[t + 256];
    __shared__ float4 red4[256];
    red4[t] = v;
    __syncthreads();
    for (int off = 128; off > 0; off >>= 1) {
      if (t < off) {
        red4[t].x += red4[t + off].x; red4[t].y += red4[t + off].y;
        red4[t].z += red4[t + off].z; red4[t].w += red4[t + off].w;
      }
      __syncthreads();
    }
    if (t == 0) {
      double link2 = (double)red4[0].x - 2.0 * (double)red4[0].z + (double)red4[0].w;
      if (link2 < 0.0) link2 = 0.0;
      out[2 * BB * DD * DD]     = (float)(sqrt(link2) / (double)((size_t)BB * NN * NN));
      out[2 * BB * DD * DD + 1] = (float)((double)red4[0].y / (double)(BB * NN));
    }
  }
}

extern "C" void kernel_launch(void* const* d_in, const int* in_sizes, int n_in,
                              void* d_out, int out_size, void* d_ws, size_t ws_size,
                              hipStream_t stream) {
  const float* x    = (const float*)d_in[0];
  const float* adj  = (const float*)d_in[1];
  const float* We1l = (const float*)d_in[2];
  const float* be1  = (const float*)d_in[3];
  const float* We1r = (const float*)d_in[4];
  const float* We2l = (const float*)d_in[5];
  const float* be2  = (const float*)d_in[6];
  const float* We2r = (const float*)d_in[7];
  const float* Wa1l = (const float*)d_in[8];
  const float* ba1  = (const float*)d_in[9];
  const float* Wa1r = (const float*)d_in[10];
  const float* Wa2l = (const float*)d_in[11];
  const float* ba2  = (const float*)d_in[12];
  const float* Wa2r = (const float*)d_in[13];
  float* out = (float*)d_out;

  const size_t MB = 1 << 20;
  char* ws = (char*)d_ws;
  float* nnzpart = (float*)(ws);                           // 512 f
  float* entpart = (float*)(ws + 4096);                    // 256 f
  float* trpart  = (float*)(ws + 8192);                    // 512 f
  float* sqpart  = (float*)(ws + 12288);                   // 512 f
  unsigned* counter = (unsigned*)(ws + 14336);             // 1 u32
  float* cnth    = (float*)(ws + 16384);                   // 128 KiB
  unsigned short* colidx = (unsigned short*)(ws + 1 * MB); // 2 MiB
  __hip_bfloat16* xbf   = (__hip_bfloat16*)(ws + 3 * MB);  // 4 MiB
  __hip_bfloat16* a1bf  = (__hip_bfloat16*)(ws + 7 * MB);  // 4 MiB
  __hip_bfloat16* h1bf  = (__hip_bfloat16*)(ws + 11 * MB); // 4 MiB
  __hip_bfloat16* Sbf   = (__hip_bfloat16*)(ws + 15 * MB); // 4 MiB
  __hip_bfloat16* STt   = (__hip_bfloat16*)(ws + 19 * MB); // 4 MiB
  __hip_bfloat16* h2T   = (__hip_bfloat16*)(ws + 23 * MB); // 4 MiB
  __hip_bfloat16* PT    = (__hip_bfloat16*)(ws + 27 * MB); // 4 MiB
  float* part           = (float*)(ws + 31 * MB);          // 12.6 MiB

  dim3 gb(32, 8, 2), glr(32, 8), glz(32, 8, 2), gtm(SPL, 24), gtr(512, 3);

  k_build<<<gb, 256, 0, stream>>>(adj, x, colidx, cnth, nnzpart, xbf, counter);
  // round 1: fused gather + dual linred (h1, a1)
  k_lin2<<<glr, 256, 0, stream>>>(xbf, colidx, cnth, We1l, We1r, be1,
                                  Wa1l, Wa1r, ba1, h1bf, a1bf);
  // round 2: fused gather + merged linreds (a2+softmax -> S/ST, h2 -> h2T)
  k_linz<<<glz, 256, 0, stream>>>(a1bf, Wa2l, Wa2r, ba2, Sbf, STt, entpart,
                                  h1bf, We2l, We2r, be2, h2T, colidx, cnth);
  // P = A^T S, transposed emission
  k_aggT<<<1024, 256, 0, stream>>>(Sbf, colidx, cnth, PT);
  // pooled outputs + fused scalar finalization
  k_tnm<<<gtm, 256, 0, stream>>>(STt, h2T, PT, part);
  k_tnred_final<<<gtr, 256, 0, stream>>>(part, out, trpart, sqpart,
                                         nnzpart, entpart, counter);
}

// Round 10
// 429.240 us; speedup vs baseline: 1.3782x; 1.3782x over previous
//
#include <hip/hip_runtime.h>
#include <hip/hip_bf16.h>
#include <math.h>

#define BB 8
#define NN 2048
#define DD 128
#define SPL 8       // K-split for the 128x128 TN MFMA GEMMs
#define CAPH 16     // per (col, quarter) capacity within one i-half

typedef __bf16 bf16x8 __attribute__((ext_vector_type(8)));
typedef float f32x4 __attribute__((ext_vector_type(4)));

__device__ inline unsigned short f2bu(float f) {
  __hip_bfloat16 h = __float2bfloat16(f);
  return *reinterpret_cast<unsigned short*>(&h);
}
__device__ inline unsigned int pack2(float a, float b) {
  return (unsigned int)f2bu(a) | ((unsigned int)f2bu(b) << 16);
}
__device__ inline float blo(unsigned u) { return __uint_as_float(u << 16); }
__device__ inline float bhi(unsigned u) { return __uint_as_float(u & 0xffff0000u); }

// Half-range pass over adj (z picks i-half): per-column 32-slot index segment,
// per-half count, per-block nnz partial. z==0 blocks also convert x to bf16.
__global__ __launch_bounds__(256) void k_build(const float* __restrict__ adj,
                                               const float* __restrict__ x,
                                               unsigned short* __restrict__ colidx,
                                               float* __restrict__ cnth,     // [2][B*NN]
                                               float* __restrict__ nnzpart,  // [512]
                                               __hip_bfloat16* __restrict__ xb,
                                               unsigned* __restrict__ counter) {
  __shared__ float T[2][64][65];
  __shared__ unsigned short L[64][4][CAPH];
  __shared__ int cnts[64][4];
  __shared__ float tsum[64];
  int b = blockIdx.y, j0 = blockIdx.x * 64, z = blockIdx.z;
  int linear = (z * 8 + blockIdx.y) * 32 + blockIdx.x;
  if (linear == 0 && threadIdx.x == 0) *counter = 0;
  const float* A = adj + (size_t)b * NN * NN + (size_t)z * 1024 * NN + j0;
  int t = threadIdx.x;
  int lr = t >> 2, lc0 = (t & 3) * 16;
  int sc = t & 63, sq = t >> 6;
  float4 pre[4];
  #pragma unroll
  for (int e = 0; e < 4; ++e)
    pre[e] = *(const float4*)(A + (size_t)lr * NN + lc0 + e * 4);
  #pragma unroll
  for (int e = 0; e < 4; ++e)
    *(float4*)&T[0][lr][lc0 + e * 4] = pre[e];
  __syncthreads();
  int cnt = 0;
  for (int ch = 0; ch < 16; ++ch) {
    if (ch + 1 < 16) {
      const float* src = A + (size_t)(ch + 1) * 64 * NN;
      #pragma unroll
      for (int e = 0; e < 4; ++e)
        pre[e] = *(const float4*)(src + (size_t)lr * NN + lc0 + e * 4);
    }
    #pragma unroll
    for (int p = 0; p < 16; ++p) {
      int il = sq * 16 + p;
      float v = T[ch & 1][il][sc];
      if (v != 0.f) {
        L[sc][sq][cnt < CAPH ? cnt : CAPH - 1] = (unsigned short)(z * 1024 + ch * 64 + il);
        ++cnt;
      }
    }
    if (ch + 1 < 16) {
      #pragma unroll
      for (int e = 0; e < 4; ++e)
        *(float4*)&T[(ch + 1) & 1][lr][lc0 + e * 4] = pre[e];
    }
    __syncthreads();
  }
  cnts[sc][sq] = cnt;
  __syncthreads();
  int c = t >> 2, seg = t & 3;
  int n0 = cnts[c][0], n1 = cnts[c][1], n2 = cnts[c][2], n3 = cnts[c][3];
  int tot = n0 + n1 + n2 + n3;
  unsigned short vals[8];
  #pragma unroll
  for (int e = 0; e < 8; ++e) {
    int k = seg * 8 + e;
    unsigned short xv = 0;
    if (k < n0) xv = L[c][0][k];
    else if (k < n0 + n1) xv = L[c][1][k - n0];
    else if (k < n0 + n1 + n2) xv = L[c][2][k - n0 - n1];
    else if (k < tot) xv = L[c][3][k - n0 - n1 - n2];
    vals[e] = xv;
  }
  size_t jg = (size_t)b * NN + j0 + c;
  *(uint4*)(colidx + jg * 64 + z * 32 + seg * 8) = *(uint4*)vals;
  if (seg == 0) {
    cnth[(size_t)z * (BB * NN) + jg] = (float)tot;
    tsum[c] = (float)tot;
  }
  __syncthreads();
  if (t < 64) {
    float s = tsum[t];
    #pragma unroll
    for (int off = 32; off > 0; off >>= 1) s += __shfl_xor(s, off);
    if (t == 0) nnzpart[linear] = s;
  }
  if (z == 0) {
    size_t base = (size_t)(blockIdx.y * 32 + blockIdx.x) * 8192;
    #pragma unroll
    for (int e = 0; e < 8; ++e) {
      size_t off = base + e * 1024 + t * 4;
      float4 a = *(const float4*)(x + off);
      unsigned r2[2] = {pack2(a.x, a.y), pack2(a.z, a.w)};
      *(uint2*)((unsigned short*)xb + off) = *(uint2*)r2;
    }
  }
}

// agg[jg][:] = (1/max(deg,1)) * sum_{i in both segments} V[b][i][:]
// wave per column: max TLP for the latency-bound gather (R9 lesson: do NOT
// fuse this into the occupancy-limited GEMM blocks).
__global__ __launch_bounds__(256) void k_agg(const __hip_bfloat16* __restrict__ V,
                                             const unsigned short* __restrict__ colidx,
                                             const float* __restrict__ cnth,
                                             __hip_bfloat16* __restrict__ out) {
  int w = threadIdx.x >> 6, l = threadIdx.x & 63;
  size_t jg = (size_t)blockIdx.x * 4 + w;
  int b = (int)(jg >> 11);
  int c0 = min((int)cnth[jg], 32);
  int c1 = min((int)cnth[(size_t)BB * NN + jg], 32);
  float sc = 1.f / fmaxf((float)(c0 + c1), 1.f);
  int myi = colidx[jg * 64 + l];
  const unsigned short* Vb = (const unsigned short*)V + (((size_t)b << 11)) * DD;
  float ax = 0.f, ay = 0.f;
  #pragma unroll
  for (int sgm = 0; sgm < 2; ++sgm) {
    int cc = sgm ? c1 : c0;
    int lb = sgm ? 32 : 0;
    int k = 0;
    for (; k + 4 <= cc; k += 4) {
      int i0 = __shfl(myi, lb + k), i1 = __shfl(myi, lb + k + 1);
      int i2 = __shfl(myi, lb + k + 2), i3 = __shfl(myi, lb + k + 3);
      unsigned u0 = *(const unsigned*)(Vb + (size_t)i0 * DD + 2 * l);
      unsigned u1 = *(const unsigned*)(Vb + (size_t)i1 * DD + 2 * l);
      unsigned u2 = *(const unsigned*)(Vb + (size_t)i2 * DD + 2 * l);
      unsigned u3 = *(const unsigned*)(Vb + (size_t)i3 * DD + 2 * l);
      ax += blo(u0) + blo(u1) + blo(u2) + blo(u3);
      ay += bhi(u0) + bhi(u1) + bhi(u2) + bhi(u3);
    }
    for (; k < cc; ++k) {
      int i0 = __shfl(myi, lb + k);
      unsigned u0 = *(const unsigned*)(Vb + (size_t)i0 * DD + 2 * l);
      ax += blo(u0); ay += bhi(u0);
    }
  }
  *(unsigned*)((unsigned short*)out + jg * DD + 2 * l) = pack2(ax * sc, ay * sc);
}

// batched: two V streams gathered with one index walk
__global__ __launch_bounds__(256) void k_agg2(const __hip_bfloat16* __restrict__ V1,
                                              const __hip_bfloat16* __restrict__ V2,
                                              const unsigned short* __restrict__ colidx,
                                              const float* __restrict__ cnth,
                                              __hip_bfloat16* __restrict__ out1,
                                              __hip_bfloat16* __restrict__ out2) {
  int w = threadIdx.x >> 6, l = threadIdx.x & 63;
  size_t jg = (size_t)blockIdx.x * 4 + w;
  int b = (int)(jg >> 11);
  int c0 = min((int)cnth[jg], 32);
  int c1 = min((int)cnth[(size_t)BB * NN + jg], 32);
  float sc = 1.f / fmaxf((float)(c0 + c1), 1.f);
  int myi = colidx[jg * 64 + l];
  size_t base = (((size_t)b << 11)) * DD + 2 * l;
  const unsigned short* Va = (const unsigned short*)V1 + base;
  const unsigned short* Vb = (const unsigned short*)V2 + base;
  float ax = 0.f, ay = 0.f, bx = 0.f, by = 0.f;
  #pragma unroll
  for (int sgm = 0; sgm < 2; ++sgm) {
    int cc = sgm ? c1 : c0;
    int lb = sgm ? 32 : 0;
    int k = 0;
    for (; k + 2 <= cc; k += 2) {
      int i0 = __shfl(myi, lb + k), i1 = __shfl(myi, lb + k + 1);
      unsigned a0 = *(const unsigned*)(Va + (size_t)i0 * DD);
      unsigned a1 = *(const unsigned*)(Va + (size_t)i1 * DD);
      unsigned b0 = *(const unsigned*)(Vb + (size_t)i0 * DD);
      unsigned b1 = *(const unsigned*)(Vb + (size_t)i1 * DD);
      ax += blo(a0) + blo(a1); ay += bhi(a0) + bhi(a1);
      bx += blo(b0) + blo(b1); by += bhi(b0) + bhi(b1);
    }
    if (k < cc) {
      int i0 = __shfl(myi, lb + k);
      unsigned a0 = *(const unsigned*)(Va + (size_t)i0 * DD);
      unsigned b0 = *(const unsigned*)(Vb + (size_t)i0 * DD);
      ax += blo(a0); ay += bhi(a0);
      bx += blo(b0); by += bhi(b0);
    }
  }
  *(unsigned*)((unsigned short*)out1 + jg * DD + 2 * l) = pack2(ax * sc, ay * sc);
  *(unsigned*)((unsigned short*)out2 + jg * DD + 2 * l) = pack2(bx * sc, by * sc);
}

// P = A^T S (unscaled), emitted TRANSPOSED: PT[b][d][t] bf16. 16 cols per block.
__global__ __launch_bounds__(256) void k_aggT(const __hip_bfloat16* __restrict__ Sbf,
                                              const unsigned short* __restrict__ colidx,
                                              const float* __restrict__ cnth,
                                              __hip_bfloat16* __restrict__ PT) {
  __shared__ float Lt[128][17];
  int w = threadIdx.x >> 6, l = threadIdx.x & 63;
  size_t jbase = (size_t)blockIdx.x * 16;
  int b = (int)(jbase >> 11);
  const unsigned short* Vb = (const unsigned short*)Sbf + (((size_t)b << 11)) * DD;
  #pragma unroll
  for (int cc4 = 0; cc4 < 4; ++cc4) {
    int jl = w * 4 + cc4;
    size_t jg = jbase + jl;
    int c0 = min((int)cnth[jg], 32);
    int c1 = min((int)cnth[(size_t)BB * NN + jg], 32);
    int myi = colidx[jg * 64 + l];
    float ax = 0.f, ay = 0.f;
    #pragma unroll
    for (int sgm = 0; sgm < 2; ++sgm) {
      int cc = sgm ? c1 : c0;
      int lb = sgm ? 32 : 0;
      int k = 0;
      for (; k + 4 <= cc; k += 4) {
        int i0 = __shfl(myi, lb + k), i1 = __shfl(myi, lb + k + 1);
        int i2 = __shfl(myi, lb + k + 2), i3 = __shfl(myi, lb + k + 3);
        unsigned u0 = *(const unsigned*)(Vb + (size_t)i0 * DD + 2 * l);
        unsigned u1 = *(const unsigned*)(Vb + (size_t)i1 * DD + 2 * l);
        unsigned u2 = *(const unsigned*)(Vb + (size_t)i2 * DD + 2 * l);
        unsigned u3 = *(const unsigned*)(Vb + (size_t)i3 * DD + 2 * l);
        ax += blo(u0) + blo(u1) + blo(u2) + blo(u3);
        ay += bhi(u0) + bhi(u1) + bhi(u2) + bhi(u3);
      }
      for (; k < cc; ++k) {
        int i0 = __shfl(myi, lb + k);
        unsigned u0 = *(const unsigned*)(Vb + (size_t)i0 * DD + 2 * l);
        ax += blo(u0); ay += bhi(u0);
      }
    }
    Lt[2 * l][jl] = ax;
    Lt[2 * l + 1][jl] = ay;
  }
  __syncthreads();
  int t = threadIdx.x;
  if (t < 128) {
    int j0 = (int)(jbase & (NN - 1));
    unsigned wv[8];
    #pragma unroll
    for (int e = 0; e < 8; ++e)
      wv[e] = pack2(Lt[t][2 * e], Lt[t][2 * e + 1]);
    unsigned short* dst = (unsigned short*)PT + ((size_t)b * DD + t) * NN + j0;
    *(uint4*)dst = *(uint4*)&wv[0];
    *(uint4*)(dst + 8) = *(uint4*)&wv[4];
  }
}

// Round-1 dual linred: stages (AGG, X2) once, computes BOTH weight sets.
__global__ __launch_bounds__(256) void k_lin2(const __hip_bfloat16* __restrict__ AGG,
                                              const __hip_bfloat16* __restrict__ X2,
                                              const float* __restrict__ W0a,
                                              const float* __restrict__ W0b,
                                              const float* __restrict__ b0,
                                              const float* __restrict__ W1a,
                                              const float* __restrict__ W1b,
                                              const float* __restrict__ b1,
                                              __hip_bfloat16* __restrict__ out0,
                                              __hip_bfloat16* __restrict__ out1) {
  __shared__ __align__(16) char smem[64 * 136 * 2 * 2];
  __shared__ __align__(16) __hip_bfloat16 Wsm[2][128 * 72];
  __shared__ float bsm[2][128];
  __hip_bfloat16* As = (__hip_bfloat16*)smem;
  __hip_bfloat16* Xs = As + 64 * 136;
  float* Ho = (float*)smem;

  int b = blockIdx.y, j0 = blockIdx.x * 64;
  int t = threadIdx.x;
  size_t rowbase = (size_t)b * NN + j0;

  if (t < 128) { bsm[0][t] = b0[t]; bsm[1][t] = b1[t]; }
  #pragma unroll
  for (int e = 0; e < 8; ++e) {
    int idx = t + e * 256;
    int r = idx >> 5, c4 = idx & 31;
    size_t g = (rowbase + r) * DD + c4 * 4;
    *(uint2*)&As[r * 136 + c4 * 4] = *(const uint2*)((const unsigned short*)AGG + g);
    *(uint2*)&Xs[r * 136 + c4 * 4] = *(const uint2*)((const unsigned short*)X2 + g);
  }
  __syncthreads();

  int w = t >> 6, l = t & 63;
  int lm = l & 15, lq = l >> 4;
  int jloc = w * 16 + lm;
  f32x4 acc0[8], acc1[8];
  #pragma unroll
  for (int mt = 0; mt < 8; ++mt)
    #pragma unroll
    for (int r = 0; r < 4; ++r) { acc0[mt][r] = 0.f; acc1[mt][r] = 0.f; }

  #pragma unroll
  for (int ph = 0; ph < 2; ++ph) {
    const __hip_bfloat16* Xt = ph ? Xs : As;
    const float* Wx = ph ? W0b : W0a;
    const float* Wy = ph ? W1b : W1a;
    #pragma unroll
    for (int ch = 0; ch < 2; ++ch) {
      __syncthreads();
      #pragma unroll
      for (int e = 0; e < 8; ++e) {
        int idx = t + e * 256;
        int o = idx >> 4, k4 = idx & 15;
        float4 wv = *(const float4*)(Wx + o * DD + ch * 64 + k4 * 4);
        uint2 pw; pw.x = pack2(wv.x, wv.y); pw.y = pack2(wv.z, wv.w);
        *(uint2*)&Wsm[0][o * 72 + k4 * 4] = pw;
        float4 wv2 = *(const float4*)(Wy + o * DD + ch * 64 + k4 * 4);
        uint2 pw2; pw2.x = pack2(wv2.x, wv2.y); pw2.y = pack2(wv2.z, wv2.w);
        *(uint2*)&Wsm[1][o * 72 + k4 * 4] = pw2;
      }
      __syncthreads();
      #pragma unroll
      for (int s = 0; s < 2; ++s) {
        int kx = ch * 64 + s * 32 + lq * 8;
        bf16x8 bfr = *(const bf16x8*)&Xt[jloc * 136 + kx];
        int kw = s * 32 + lq * 8;
        #pragma unroll
        for (int mt = 0; mt < 8; ++mt) {
          bf16x8 a0 = *(const bf16x8*)&Wsm[0][(mt * 16 + lm) * 72 + kw];
          acc0[mt] = __builtin_amdgcn_mfma_f32_16x16x32_bf16(a0, bfr, acc0[mt], 0, 0, 0);
          bf16x8 a1 = *(const bf16x8*)&Wsm[1][(mt * 16 + lm) * 72 + kw];
          acc1[mt] = __builtin_amdgcn_mfma_f32_16x16x32_bf16(a1, bfr, acc1[mt], 0, 0, 0);
        }
      }
    }
  }

  #pragma unroll
  for (int set = 0; set < 2; ++set) {
    __syncthreads();
    f32x4* acc = set ? acc1 : acc0;
    float psum = 0.f;
    float hv[8][4];
    #pragma unroll
    for (int mt = 0; mt < 8; ++mt)
      #pragma unroll
      for (int r = 0; r < 4; ++r) {
        int o = mt * 16 + lq * 4 + r;
        float v = fmaxf(acc[mt][r] + bsm[set][o], 0.f);
        hv[mt][r] = v;
        psum += v * v;
      }
    psum += __shfl_xor(psum, 16);
    psum += __shfl_xor(psum, 32);
    float rn = 1.f / (sqrtf(psum) + 1e-9f);
    #pragma unroll
    for (int mt = 0; mt < 8; ++mt)
      #pragma unroll
      for (int r = 0; r < 4; ++r) {
        int o = mt * 16 + lq * 4 + r;
        Ho[jloc * 132 + o] = hv[mt][r] * rn;
      }
    __syncthreads();
    __hip_bfloat16* ob = set ? out1 : out0;
    #pragma unroll
    for (int e = 0; e < 4; ++e) {
      int idx = t + e * 256;
      int r = idx >> 4, c8 = idx & 15;
      const float* h = &Ho[r * 132 + c8 * 8];
      unsigned pk[4] = {pack2(h[0], h[1]), pack2(h[2], h[3]),
                        pack2(h[4], h[5]), pack2(h[6], h[7])};
      *(uint4*)((unsigned short*)ob + (rowbase + r) * DD + c8 * 8) = *(uint4*)pk;
    }
  }
}

// Round-2 merged linred. z=0: assignment branch with FUSED softmax epilogue
// (emits Sbf row-major, STt transposed, per-block entropy). z=1: embedding
// branch, l2norm epilogue, transposed bf16 h2T out.
__global__ __launch_bounds__(256) void k_linz(const __hip_bfloat16* __restrict__ AG0,
                                              const __hip_bfloat16* __restrict__ X0,
                                              const float* __restrict__ W0a,
                                              const float* __restrict__ W0b,
                                              const float* __restrict__ b0,
                                              __hip_bfloat16* __restrict__ Sbf,
                                              __hip_bfloat16* __restrict__ STt,
                                              float* __restrict__ entpart,
                                              const __hip_bfloat16* __restrict__ AG1,
                                              const __hip_bfloat16* __restrict__ X1,
                                              const float* __restrict__ W1a,
                                              const float* __restrict__ W1b,
                                              const float* __restrict__ b1,
                                              __hip_bfloat16* __restrict__ out1T) {
  __shared__ __align__(16) char smem[64 * 136 * 2 * 2];
  __shared__ __align__(16) __hip_bfloat16 Wsm[128 * 72];
  __shared__ float bsm[128];
  __shared__ float entred[64];
  __hip_bfloat16* As = (__hip_bfloat16*)smem;
  __hip_bfloat16* Xs = As + 64 * 136;
  float* Ho = (float*)smem;

  int mode = blockIdx.z;
  const __hip_bfloat16* AGG = mode ? AG1 : AG0;
  const __hip_bfloat16* X2 = mode ? X1 : X0;
  const float* Wl = mode ? W1a : W0a;
  const float* Wr = mode ? W1b : W0b;
  const float* bias = mode ? b1 : b0;

  int b = blockIdx.y, j0 = blockIdx.x * 64;
  int t = threadIdx.x;
  size_t rowbase = (size_t)b * NN + j0;

  if (t < 128) bsm[t] = bias[t];
  #pragma unroll
  for (int e = 0; e < 8; ++e) {
    int idx = t + e * 256;
    int r = idx >> 5, c4 = idx & 31;
    size_t g = (rowbase + r) * DD + c4 * 4;
    *(uint2*)&As[r * 136 + c4 * 4] = *(const uint2*)((const unsigned short*)AGG + g);
    *(uint2*)&Xs[r * 136 + c4 * 4] = *(const uint2*)((const unsigned short*)X2 + g);
  }
  __syncthreads();

  int w = t >> 6, l = t & 63;
  int lm = l & 15, lq = l >> 4;
  int jloc = w * 16 + lm;
  f32x4 acc[8];
  #pragma unroll
  for (int mt = 0; mt < 8; ++mt)
    #pragma unroll
    for (int r = 0; r < 4; ++r) acc[mt][r] = 0.f;

  #pragma unroll
  for (int ph = 0; ph < 2; ++ph) {
    const __hip_bfloat16* Xt = ph ? Xs : As;
    const float* W = ph ? Wr : Wl;
    #pragma unroll
    for (int ch = 0; ch < 2; ++ch) {
      __syncthreads();
      #pragma unroll
      for (int e = 0; e < 8; ++e) {
        int idx = t + e * 256;
        int o = idx >> 4, k4 = idx & 15;
        float4 wv = *(const float4*)(W + o * DD + ch * 64 + k4 * 4);
        uint2 pw; pw.x = pack2(wv.x, wv.y); pw.y = pack2(wv.z, wv.w);
        *(uint2*)&Wsm[o * 72 + k4 * 4] = pw;
      }
      __syncthreads();
      #pragma unroll
      for (int s = 0; s < 2; ++s) {
        int kx = ch * 64 + s * 32 + lq * 8;
        bf16x8 bfr = *(const bf16x8*)&Xt[jloc * 136 + kx];
        int kw = s * 32 + lq * 8;
        #pragma unroll
        for (int mt = 0; mt < 8; ++mt) {
          bf16x8 afr = *(const bf16x8*)&Wsm[(mt * 16 + lm) * 72 + kw];
          acc[mt] = __builtin_amdgcn_mfma_f32_16x16x32_bf16(afr, bfr, acc[mt], 0, 0, 0);
        }
      }
    }
  }

  __syncthreads();
  float hv[8][4];
  float psum = 0.f;
  #pragma unroll
  for (int mt = 0; mt < 8; ++mt)
    #pragma unroll
    for (int r = 0; r < 4; ++r) {
      int o = mt * 16 + lq * 4 + r;
      float v = fmaxf(acc[mt][r] + bsm[o], 0.f);
      hv[mt][r] = v;
      psum += v * v;
    }
  psum += __shfl_xor(psum, 16);
  psum += __shfl_xor(psum, 32);
  float rn = 1.f / (sqrtf(psum) + 1e-9f);

  if (mode == 0) {
    float av[8][4];
    float m = -3.4e38f;
    #pragma unroll
    for (int mt = 0; mt < 8; ++mt)
      #pragma unroll
      for (int r = 0; r < 4; ++r) {
        float a = hv[mt][r] * rn;
        av[mt][r] = a;
        m = fmaxf(m, a);
      }
    m = fmaxf(m, __shfl_xor(m, 16));
    m = fmaxf(m, __shfl_xor(m, 32));
    float sum = 0.f;
    #pragma unroll
    for (int mt = 0; mt < 8; ++mt)
      #pragma unroll
      for (int r = 0; r < 4; ++r) {
        float e = expf(av[mt][r] - m);
        av[mt][r] = e;
        sum += e;
      }
    sum += __shfl_xor(sum, 16);
    sum += __shfl_xor(sum, 32);
    float inv = 1.f / sum;
    float ent = 0.f;
    #pragma unroll
    for (int mt = 0; mt < 8; ++mt)
      #pragma unroll
      for (int r = 0; r < 4; ++r) {
        float p = av[mt][r] * inv;
        ent -= p * logf(p + 1e-15f);
        int o = mt * 16 + lq * 4 + r;
        Ho[jloc * 132 + o] = p;
      }
    ent += __shfl_xor(ent, 16);
    ent += __shfl_xor(ent, 32);
    if (l < 16) entred[w * 16 + lm] = ent;
    __syncthreads();
    #pragma unroll
    for (int e = 0; e < 4; ++e) {
      int idx = t + e * 256;
      int r = idx >> 4, c8 = idx & 15;
      const float* h = &Ho[r * 132 + c8 * 8];
      unsigned pk[4] = {pack2(h[0], h[1]), pack2(h[2], h[3]),
                        pack2(h[4], h[5]), pack2(h[6], h[7])};
      *(uint4*)((unsigned short*)Sbf + (rowbase + r) * DD + c8 * 8) = *(uint4*)pk;
    }
    {
      int d = t >> 1, half = t & 1;
      unsigned wv[16];
      #pragma unroll
      for (int e = 0; e < 16; ++e)
        wv[e] = pack2(Ho[(half * 32 + 2 * e) * 132 + d], Ho[(half * 32 + 2 * e + 1) * 132 + d]);
      unsigned short* dst = (unsigned short*)STt + ((size_t)b * DD + d) * NN + j0 + half * 32;
      #pragma unroll
      for (int q = 0; q < 4; ++q)
        *(uint4*)(dst + q * 8) = *(uint4*)&wv[q * 4];
    }
    if (t < 64) {
      float s = entred[t];
      #pragma unroll
      for (int off = 32; off > 0; off >>= 1) s += __shfl_xor(s, off);
      if (t == 0) entpart[blockIdx.y * 32 + blockIdx.x] = s;
    }
  } else {
    #pragma unroll
    for (int mt = 0; mt < 8; ++mt)
      #pragma unroll
      for (int r = 0; r < 4; ++r) {
        int o = mt * 16 + lq * 4 + r;
        Ho[jloc * 132 + o] = hv[mt][r] * rn;
      }
    __syncthreads();
    int d = t >> 1, half = t & 1;
    unsigned wv[16];
    #pragma unroll
    for (int e = 0; e < 16; ++e)
      wv[e] = pack2(Ho[(half * 32 + 2 * e) * 132 + d], Ho[(half * 32 + 2 * e + 1) * 132 + d]);
    unsigned short* dst = (unsigned short*)out1T + ((size_t)b * DD + d) * NN + j0 + half * 32;
    #pragma unroll
    for (int q = 0; q < 4; ++q)
      *(uint4*)(dst + q * 8) = *(uint4*)&wv[q * 4];
  }
}

// TN MFMA: pair0 ST·h2T^T (h_pooled), pair1 PT·ST^T (adj_pooled), pair2 ST·ST^T (G)
__global__ __launch_bounds__(256) void k_tnm(const __hip_bfloat16* __restrict__ ST,
                                             const __hip_bfloat16* __restrict__ HT,
                                             const __hip_bfloat16* __restrict__ PT,
                                             float* __restrict__ part) {
  __shared__ __align__(16) __hip_bfloat16 As[128 * 64];
  __shared__ __align__(16) __hip_bfloat16 Bs[128 * 64];
  int pb = blockIdx.y;
  int pair = pb >> 3, b = pb & 7;
  const __hip_bfloat16* Xa = (pair == 1) ? PT : ST;
  const __hip_bfloat16* Ya = (pair == 0) ? HT : ST;
  const __hip_bfloat16* Ab = Xa + (size_t)b * DD * NN;
  const __hip_bfloat16* Bb = Ya + (size_t)b * DD * NN;
  int k0 = blockIdx.x * (NN / SPL);
  int tid = threadIdx.x;
  int w = tid >> 6, l = tid & 63;
  int wj = w & 1, wd = w >> 1;
  int sr = l >> 3, ss = l & 7;
  int lm = l & 15, lq = l >> 4;
  f32x4 acc[4][4];
  #pragma unroll
  for (int a = 0; a < 4; ++a)
    #pragma unroll
    for (int c = 0; c < 4; ++c)
      #pragma unroll
      for (int r = 0; r < 4; ++r) acc[a][c][r] = 0.f;

  for (int kb = 0; kb < (NN / SPL) / 64; ++kb) {
    int kbase = k0 + kb * 64;
    __syncthreads();
    #pragma unroll
    for (int e = 0; e < 4; ++e) {
      int r = 32 * w + 8 * e + sr;
      int g = ss ^ (r & 7);
      const __hip_bfloat16* srcA = Ab + (size_t)r * NN + kbase + g * 8;
      __builtin_amdgcn_global_load_lds(
          (const __attribute__((address_space(1))) void*)srcA,
          (__attribute__((address_space(3))) void*)&As[(32 * w + 8 * e) * 64], 16, 0, 0);
      const __hip_bfloat16* srcB = Bb + (size_t)r * NN + kbase + g * 8;
      __builtin_amdgcn_global_load_lds(
          (const __attribute__((address_space(1))) void*)srcB,
          (__attribute__((address_space(3))) void*)&Bs[(32 * w + 8 * e) * 64], 16, 0, 0);
    }
    __syncthreads();
    #pragma unroll
    for (int ks = 0; ks < 2; ++ks) {
      bf16x8 afr[4], bfr[4];
      int kg = ks * 4 + lq;
      #pragma unroll
      for (int jt = 0; jt < 4; ++jt) {
        int jl = wj * 64 + jt * 16 + lm;
        afr[jt] = *(const bf16x8*)&As[jl * 64 + ((kg ^ (jl & 7)) << 3)];
      }
      #pragma unroll
      for (int dt = 0; dt < 4; ++dt) {
        int dl = wd * 64 + dt * 16 + lm;
        bfr[dt] = *(const bf16x8*)&Bs[dl * 64 + ((kg ^ (dl & 7)) << 3)];
      }
      #pragma unroll
      for (int jt = 0; jt < 4; ++jt)
        #pragma unroll
        for (int dt = 0; dt < 4; ++dt)
          acc[jt][dt] = __builtin_amdgcn_mfma_f32_16x16x32_bf16(afr[jt], bfr[dt], acc[jt][dt], 0, 0, 0);
    }
  }
  float* P = part + ((size_t)(pair * SPL + blockIdx.x) * BB + b) * DD * DD;
  #pragma unroll
  for (int jt = 0; jt < 4; ++jt)
    #pragma unroll
    for (int reg = 0; reg < 4; ++reg) {
      int j = wj * 64 + jt * 16 + lq * 4 + reg;
      float* row = P + (size_t)j * DD;
      #pragma unroll
      for (int dt = 0; dt < 4; ++dt)
        row[wd * 64 + dt * 16 + lm] = acc[jt][dt][reg];
    }
}

// reduce SPL partials; last finishing block computes the two loss scalars.
__global__ __launch_bounds__(256) void k_tnred_final(const float* __restrict__ part,
                                                     float* __restrict__ out,
                                                     float* __restrict__ trpart,
                                                     float* __restrict__ sqpart,
                                                     const float* __restrict__ nnzpart,
                                                     const float* __restrict__ entpart,
                                                     unsigned* __restrict__ counter) {
  __shared__ float red[256];
  int pair = blockIdx.y;
  size_t i = (size_t)blockIdx.x * 256 + threadIdx.x;     // < B*D*D = 131072
  float s = 0.f;
  #pragma unroll
  for (int ks = 0; ks < SPL; ++ks)
    s += part[((size_t)pair * SPL + ks) * (BB * DD * DD) + i];
  float contrib = 0.f;
  if (pair == 0) {
    out[i] = s;
  } else if (pair == 1) {
    out[(size_t)BB * DD * DD + i] = s;
    int rc = (int)(i & (DD * DD - 1));
    if ((rc >> 7) == (rc & 127)) contrib = s;
  } else {
    contrib = s * s;
  }
  red[threadIdx.x] = contrib;
  __syncthreads();
  for (int off = 128; off > 0; off >>= 1) {
    if (threadIdx.x < off) red[threadIdx.x] += red[threadIdx.x + off];
    __syncthreads();
  }
  if (threadIdx.x == 0) {
    if (pair == 1) trpart[blockIdx.x] = red[0];
    else if (pair == 2) sqpart[blockIdx.x] = red[0];
  }
  __threadfence();
  __shared__ unsigned last;
  if (threadIdx.x == 0) last = atomicAdd(counter, 1u);
  __syncthreads();
  if (last == 3 * 512 - 1) {
    __threadfence();
    int t = threadIdx.x;
    float4 v;
    v.x = nnzpart[t] + nnzpart[t + 256];
    v.y = entpart[t];
    v.z = trpart[t] + trpart[t + 256];
    v.w = sqpart[t] + sqpart[t + 256];
    __shared__ float4 red4[256];
    red4[t] = v;
    __syncthreads();
    for (int off = 128; off > 0; off >>= 1) {
      if (t < off) {
        red4[t].x += red4[t + off].x; red4[t].y += red4[t + off].y;
        red4[t].z += red4[t + off].z; red4[t].w += red4[t + off].w;
      }
      __syncthreads();
    }
    if (t == 0) {
      double link2 = (double)red4[0].x - 2.0 * (double)red4[0].z + (double)red4[0].w;
      if (link2 < 0.0) link2 = 0.0;
      out[2 * BB * DD * DD]     = (float)(sqrt(link2) / (double)((size_t)BB * NN * NN));
      out[2 * BB * DD * DD + 1] = (float)((double)red4[0].y / (double)(BB * NN));
    }
  }
}

extern "C" void kernel_launch(void* const* d_in, const int* in_sizes, int n_in,
                              void* d_out, int out_size, void* d_ws, size_t ws_size,
                              hipStream_t stream) {
  const float* x    = (const float*)d_in[0];
  const float* adj  = (const float*)d_in[1];
  const float* We1l = (const float*)d_in[2];
  const float* be1  = (const float*)d_in[3];
  const float* We1r = (const float*)d_in[4];
  const float* We2l = (const float*)d_in[5];
  const float* be2  = (const float*)d_in[6];
  const float* We2r = (const float*)d_in[7];
  const float* Wa1l = (const float*)d_in[8];
  const float* ba1  = (const float*)d_in[9];
  const float* Wa1r = (const float*)d_in[10];
  const float* Wa2l = (const float*)d_in[11];
  const float* ba2  = (const float*)d_in[12];
  const float* Wa2r = (const float*)d_in[13];
  float* out = (float*)d_out;

  const size_t MB = 1 << 20;
  char* ws = (char*)d_ws;
  float* nnzpart = (float*)(ws);                           // 512 f
  float* entpart = (float*)(ws + 4096);                    // 256 f
  float* trpart  = (float*)(ws + 8192);                    // 512 f
  float* sqpart  = (float*)(ws + 12288);                   // 512 f
  unsigned* counter = (unsigned*)(ws + 14336);             // 1 u32
  float* cnth    = (float*)(ws + 16384);                   // 128 KiB
  unsigned short* colidx = (unsigned short*)(ws + 1 * MB); // 2 MiB
  __hip_bfloat16* xbf   = (__hip_bfloat16*)(ws + 3 * MB);  // 4 MiB
  __hip_bfloat16* agg1  = (__hip_bfloat16*)(ws + 7 * MB);  // 4 MiB (also agg2a)
  __hip_bfloat16* agg2h = (__hip_bfloat16*)(ws + 11 * MB); // 4 MiB
  __hip_bfloat16* a1bf  = (__hip_bfloat16*)(ws + 15 * MB); // 4 MiB
  __hip_bfloat16* h1bf  = (__hip_bfloat16*)(ws + 19 * MB); // 4 MiB
  __hip_bfloat16* Sbf   = (__hip_bfloat16*)(ws + 23 * MB); // 4 MiB
  __hip_bfloat16* STt   = (__hip_bfloat16*)(ws + 27 * MB); // 4 MiB
  __hip_bfloat16* h2T   = (__hip_bfloat16*)(ws + 31 * MB); // 4 MiB
  __hip_bfloat16* PT    = (__hip_bfloat16*)(ws + 35 * MB); // 4 MiB
  float* part           = (float*)(ws + 39 * MB);          // 12.6 MiB

  dim3 gb(32, 8, 2), glr(32, 8), glz(32, 8, 2), gtm(SPL, 24), gtr(512, 3);

  k_build<<<gb, 256, 0, stream>>>(adj, x, colidx, cnth, nnzpart, xbf, counter);
  // round 1: shared mean-aggregation of x (high-TLP), dual linred (h1, a1)
  k_agg<<<4096, 256, 0, stream>>>(xbf, colidx, cnth, agg1);
  k_lin2<<<glr, 256, 0, stream>>>(agg1, xbf, We1l, We1r, be1, Wa1l, Wa1r, ba1, h1bf, a1bf);
  // round 2: batched aggregation of (a1, h1); merged linreds (a2+softmax, h2T)
  k_agg2<<<4096, 256, 0, stream>>>(a1bf, h1bf, colidx, cnth, agg1, agg2h);
  k_linz<<<glz, 256, 0, stream>>>(agg1, a1bf, Wa2l, Wa2r, ba2, Sbf, STt, entpart,
                                  agg2h, h1bf, We2l, We2r, be2, h2T);
  // P = A^T S, transposed emission
  k_aggT<<<1024, 256, 0, stream>>>(Sbf, colidx, cnth, PT);
  // pooled outputs + fused scalar finalization
  k_tnm<<<gtm, 256, 0, stream>>>(STt, h2T, PT, part);
  k_tnred_final<<<gtr, 256, 0, stream>>>(part, out, trpart, sqpart,
                                         nnzpart, entpart, counter);
}

// Round 11
// 310.712 us; speedup vs baseline: 1.9039x; 1.3815x over previous
//
#include <hip/hip_runtime.h>
#include <hip/hip_bf16.h>
#include <math.h>

#define BB 8
#define NN 2048
#define DD 128
#define SPL 8       // K-split for the 128x128 TN MFMA GEMMs
#define CAPH 16     // per (col, quarter) capacity within one i-half (mean 2.56, ~8 sigma)

typedef __bf16 bf16x8 __attribute__((ext_vector_type(8)));
typedef float f32x4 __attribute__((ext_vector_type(4)));

__device__ inline unsigned short f2bu(float f) {
  __hip_bfloat16 h = __float2bfloat16(f);
  return *reinterpret_cast<unsigned short*>(&h);
}
__device__ inline unsigned int pack2(float a, float b) {
  return (unsigned int)f2bu(a) | ((unsigned int)f2bu(b) << 16);
}
__device__ inline float blo(unsigned u) { return __uint_as_float(u << 16); }
__device__ inline float bhi(unsigned u) { return __uint_as_float(u & 0xffff0000u); }

// Half-range pass over adj (z picks i-half): per-column 32-slot index segment,
// per-half count, per-block nnz partial. z==0 blocks also convert x to bf16.
__global__ __launch_bounds__(256) void k_build(const float* __restrict__ adj,
                                               const float* __restrict__ x,
                                               unsigned short* __restrict__ colidx,
                                               float* __restrict__ cnth,     // [2][B*NN]
                                               float* __restrict__ nnzpart,  // [512]
                                               __hip_bfloat16* __restrict__ xb) {
  __shared__ float T[2][64][65];
  __shared__ unsigned short L[64][4][CAPH];
  __shared__ int cnts[64][4];
  __shared__ float tsum[64];
  int b = blockIdx.y, j0 = blockIdx.x * 64, z = blockIdx.z;
  int linear = (z * 8 + blockIdx.y) * 32 + blockIdx.x;
  const float* A = adj + (size_t)b * NN * NN + (size_t)z * 1024 * NN + j0;
  int t = threadIdx.x;
  int lr = t >> 2, lc0 = (t & 3) * 16;
  int sc = t & 63, sq = t >> 6;
  float4 pre[4];
  #pragma unroll
  for (int e = 0; e < 4; ++e)
    pre[e] = *(const float4*)(A + (size_t)lr * NN + lc0 + e * 4);
  #pragma unroll
  for (int e = 0; e < 4; ++e)
    *(float4*)&T[0][lr][lc0 + e * 4] = pre[e];
  __syncthreads();
  int cnt = 0;
  for (int ch = 0; ch < 16; ++ch) {
    if (ch + 1 < 16) {
      const float* src = A + (size_t)(ch + 1) * 64 * NN;
      #pragma unroll
      for (int e = 0; e < 4; ++e)
        pre[e] = *(const float4*)(src + (size_t)lr * NN + lc0 + e * 4);
    }
    #pragma unroll
    for (int p = 0; p < 16; ++p) {
      int il = sq * 16 + p;
      float v = T[ch & 1][il][sc];
      if (v != 0.f) {
        L[sc][sq][cnt < CAPH ? cnt : CAPH - 1] = (unsigned short)(z * 1024 + ch * 64 + il);
        ++cnt;
      }
    }
    if (ch + 1 < 16) {
      #pragma unroll
      for (int e = 0; e < 4; ++e)
        *(float4*)&T[(ch + 1) & 1][lr][lc0 + e * 4] = pre[e];
    }
    __syncthreads();
  }
  cnts[sc][sq] = cnt;
  __syncthreads();
  int c = t >> 2, seg = t & 3;
  int n0 = cnts[c][0], n1 = cnts[c][1], n2 = cnts[c][2], n3 = cnts[c][3];
  int tot = n0 + n1 + n2 + n3;
  unsigned short vals[8];
  #pragma unroll
  for (int e = 0; e < 8; ++e) {
    int k = seg * 8 + e;
    unsigned short xv = 0;
    if (k < n0) xv = L[c][0][k];
    else if (k < n0 + n1) xv = L[c][1][k - n0];
    else if (k < n0 + n1 + n2) xv = L[c][2][k - n0 - n1];
    else if (k < tot) xv = L[c][3][k - n0 - n1 - n2];
    vals[e] = xv;
  }
  size_t jg = (size_t)b * NN + j0 + c;
  *(uint4*)(colidx + jg * 64 + z * 32 + seg * 8) = *(uint4*)vals;
  if (seg == 0) {
    cnth[(size_t)z * (BB * NN) + jg] = (float)tot;
    tsum[c] = (float)tot;
  }
  __syncthreads();
  if (t < 64) {
    float s = tsum[t];
    #pragma unroll
    for (int off = 32; off > 0; off >>= 1) s += __shfl_xor(s, off);
    if (t == 0) nnzpart[linear] = s;
  }
  if (z == 0) {
    size_t base = (size_t)(blockIdx.y * 32 + blockIdx.x) * 8192;
    #pragma unroll
    for (int e = 0; e < 8; ++e) {
      size_t off = base + e * 1024 + t * 4;
      float4 a = *(const float4*)(x + off);
      unsigned r2[2] = {pack2(a.x, a.y), pack2(a.z, a.w)};
      *(uint2*)((unsigned short*)xb + off) = *(uint2*)r2;
    }
  }
}

// agg[jg][:] = (1/max(deg,1)) * sum_{i in both segments} V[b][i][:]
// wave per column: max TLP for the latency-bound gather (R9 lesson: do NOT
// fuse this into the occupancy-limited GEMM blocks).
__global__ __launch_bounds__(256) void k_agg(const __hip_bfloat16* __restrict__ V,
                                             const unsigned short* __restrict__ colidx,
                                             const float* __restrict__ cnth,
                                             __hip_bfloat16* __restrict__ out) {
  int w = threadIdx.x >> 6, l = threadIdx.x & 63;
  size_t jg = (size_t)blockIdx.x * 4 + w;
  int b = (int)(jg >> 11);
  int c0 = min((int)cnth[jg], 32);
  int c1 = min((int)cnth[(size_t)BB * NN + jg], 32);
  float sc = 1.f / fmaxf((float)(c0 + c1), 1.f);
  int myi = colidx[jg * 64 + l];
  const unsigned short* Vb = (const unsigned short*)V + (((size_t)b << 11)) * DD;
  float ax = 0.f, ay = 0.f;
  #pragma unroll
  for (int sgm = 0; sgm < 2; ++sgm) {
    int cc = sgm ? c1 : c0;
    int lb = sgm ? 32 : 0;
    int k = 0;
    for (; k + 4 <= cc; k += 4) {
      int i0 = __shfl(myi, lb + k), i1 = __shfl(myi, lb + k + 1);
      int i2 = __shfl(myi, lb + k + 2), i3 = __shfl(myi, lb + k + 3);
      unsigned u0 = *(const unsigned*)(Vb + (size_t)i0 * DD + 2 * l);
      unsigned u1 = *(const unsigned*)(Vb + (size_t)i1 * DD + 2 * l);
      unsigned u2 = *(const unsigned*)(Vb + (size_t)i2 * DD + 2 * l);
      unsigned u3 = *(const unsigned*)(Vb + (size_t)i3 * DD + 2 * l);
      ax += blo(u0) + blo(u1) + blo(u2) + blo(u3);
      ay += bhi(u0) + bhi(u1) + bhi(u2) + bhi(u3);
    }
    for (; k < cc; ++k) {
      int i0 = __shfl(myi, lb + k);
      unsigned u0 = *(const unsigned*)(Vb + (size_t)i0 * DD + 2 * l);
      ax += blo(u0); ay += bhi(u0);
    }
  }
  *(unsigned*)((unsigned short*)out + jg * DD + 2 * l) = pack2(ax * sc, ay * sc);
}

// batched: two V streams gathered with one index walk
__global__ __launch_bounds__(256) void k_agg2(const __hip_bfloat16* __restrict__ V1,
                                              const __hip_bfloat16* __restrict__ V2,
                                              const unsigned short* __restrict__ colidx,
                                              const float* __restrict__ cnth,
                                              __hip_bfloat16* __restrict__ out1,
                                              __hip_bfloat16* __restrict__ out2) {
  int w = threadIdx.x >> 6, l = threadIdx.x & 63;
  size_t jg = (size_t)blockIdx.x * 4 + w;
  int b = (int)(jg >> 11);
  int c0 = min((int)cnth[jg], 32);
  int c1 = min((int)cnth[(size_t)BB * NN + jg], 32);
  float sc = 1.f / fmaxf((float)(c0 + c1), 1.f);
  int myi = colidx[jg * 64 + l];
  size_t base = (((size_t)b << 11)) * DD + 2 * l;
  const unsigned short* Va = (const unsigned short*)V1 + base;
  const unsigned short* Vb = (const unsigned short*)V2 + base;
  float ax = 0.f, ay = 0.f, bx = 0.f, by = 0.f;
  #pragma unroll
  for (int sgm = 0; sgm < 2; ++sgm) {
    int cc = sgm ? c1 : c0;
    int lb = sgm ? 32 : 0;
    int k = 0;
    for (; k + 2 <= cc; k += 2) {
      int i0 = __shfl(myi, lb + k), i1 = __shfl(myi, lb + k + 1);
      unsigned a0 = *(const unsigned*)(Va + (size_t)i0 * DD);
      unsigned a1 = *(const unsigned*)(Va + (size_t)i1 * DD);
      unsigned b0 = *(const unsigned*)(Vb + (size_t)i0 * DD);
      unsigned b1 = *(const unsigned*)(Vb + (size_t)i1 * DD);
      ax += blo(a0) + blo(a1); ay += bhi(a0) + bhi(a1);
      bx += blo(b0) + blo(b1); by += bhi(b0) + bhi(b1);
    }
    if (k < cc) {
      int i0 = __shfl(myi, lb + k);
      unsigned a0 = *(const unsigned*)(Va + (size_t)i0 * DD);
      unsigned b0 = *(const unsigned*)(Vb + (size_t)i0 * DD);
      ax += blo(a0); ay += bhi(a0);
      bx += blo(b0); by += bhi(b0);
    }
  }
  *(unsigned*)((unsigned short*)out1 + jg * DD + 2 * l) = pack2(ax * sc, ay * sc);
  *(unsigned*)((unsigned short*)out2 + jg * DD + 2 * l) = pack2(bx * sc, by * sc);
}

// P = A^T S (unscaled), emitted TRANSPOSED: PT[b][d][t] bf16. 16 cols per block.
__global__ __launch_bounds__(256) void k_aggT(const __hip_bfloat16* __restrict__ Sbf,
                                              const unsigned short* __restrict__ colidx,
                                              const float* __restrict__ cnth,
                                              __hip_bfloat16* __restrict__ PT) {
  __shared__ float Lt[128][17];
  int w = threadIdx.x >> 6, l = threadIdx.x & 63;
  size_t jbase = (size_t)blockIdx.x * 16;
  int b = (int)(jbase >> 11);
  const unsigned short* Vb = (const unsigned short*)Sbf + (((size_t)b << 11)) * DD;
  #pragma unroll
  for (int cc4 = 0; cc4 < 4; ++cc4) {
    int jl = w * 4 + cc4;
    size_t jg = jbase + jl;
    int c0 = min((int)cnth[jg], 32);
    int c1 = min((int)cnth[(size_t)BB * NN + jg], 32);
    int myi = colidx[jg * 64 + l];
    float ax = 0.f, ay = 0.f;
    #pragma unroll
    for (int sgm = 0; sgm < 2; ++sgm) {
      int cc = sgm ? c1 : c0;
      int lb = sgm ? 32 : 0;
      int k = 0;
      for (; k + 4 <= cc; k += 4) {
        int i0 = __shfl(myi, lb + k), i1 = __shfl(myi, lb + k + 1);
        int i2 = __shfl(myi, lb + k + 2), i3 = __shfl(myi, lb + k + 3);
        unsigned u0 = *(const unsigned*)(Vb + (size_t)i0 * DD + 2 * l);
        unsigned u1 = *(const unsigned*)(Vb + (size_t)i1 * DD + 2 * l);
        unsigned u2 = *(const unsigned*)(Vb + (size_t)i2 * DD + 2 * l);
        unsigned u3 = *(const unsigned*)(Vb + (size_t)i3 * DD + 2 * l);
        ax += blo(u0) + blo(u1) + blo(u2) + blo(u3);
        ay += bhi(u0) + bhi(u1) + bhi(u2) + bhi(u3);
      }
      for (; k < cc; ++k) {
        int i0 = __shfl(myi, lb + k);
        unsigned u0 = *(const unsigned*)(Vb + (size_t)i0 * DD + 2 * l);
        ax += blo(u0); ay += bhi(u0);
      }
    }
    Lt[2 * l][jl] = ax;
    Lt[2 * l + 1][jl] = ay;
  }
  __syncthreads();
  int t = threadIdx.x;
  if (t < 128) {
    int j0 = (int)(jbase & (NN - 1));
    unsigned wv[8];
    #pragma unroll
    for (int e = 0; e < 8; ++e)
      wv[e] = pack2(Lt[t][2 * e], Lt[t][2 * e + 1]);
    unsigned short* dst = (unsigned short*)PT + ((size_t)b * DD + t) * NN + j0;
    *(uint4*)dst = *(uint4*)&wv[0];
    *(uint4*)(dst + 8) = *(uint4*)&wv[4];
  }
}

// Round-1 dual linred: stages (AGG, X2) once, computes BOTH weight sets.
__global__ __launch_bounds__(256) void k_lin2(const __hip_bfloat16* __restrict__ AGG,
                                              const __hip_bfloat16* __restrict__ X2,
                                              const float* __restrict__ W0a,
                                              const float* __restrict__ W0b,
                                              const float* __restrict__ b0,
                                              const float* __restrict__ W1a,
                                              const float* __restrict__ W1b,
                                              const float* __restrict__ b1,
                                              __hip_bfloat16* __restrict__ out0,
                                              __hip_bfloat16* __restrict__ out1) {
  __shared__ __align__(16) char smem[64 * 136 * 2 * 2];
  __shared__ __align__(16) __hip_bfloat16 Wsm[2][128 * 72];
  __shared__ float bsm[2][128];
  __hip_bfloat16* As = (__hip_bfloat16*)smem;
  __hip_bfloat16* Xs = As + 64 * 136;
  float* Ho = (float*)smem;

  int b = blockIdx.y, j0 = blockIdx.x * 64;
  int t = threadIdx.x;
  size_t rowbase = (size_t)b * NN + j0;

  if (t < 128) { bsm[0][t] = b0[t]; bsm[1][t] = b1[t]; }
  #pragma unroll
  for (int e = 0; e < 8; ++e) {
    int idx = t + e * 256;
    int r = idx >> 5, c4 = idx & 31;
    size_t g = (rowbase + r) * DD + c4 * 4;
    *(uint2*)&As[r * 136 + c4 * 4] = *(const uint2*)((const unsigned short*)AGG + g);
    *(uint2*)&Xs[r * 136 + c4 * 4] = *(const uint2*)((const unsigned short*)X2 + g);
  }
  __syncthreads();

  int w = t >> 6, l = t & 63;
  int lm = l & 15, lq = l >> 4;
  int jloc = w * 16 + lm;
  f32x4 acc0[8], acc1[8];
  #pragma unroll
  for (int mt = 0; mt < 8; ++mt)
    #pragma unroll
    for (int r = 0; r < 4; ++r) { acc0[mt][r] = 0.f; acc1[mt][r] = 0.f; }

  #pragma unroll
  for (int ph = 0; ph < 2; ++ph) {
    const __hip_bfloat16* Xt = ph ? Xs : As;
    const float* Wx = ph ? W0b : W0a;
    const float* Wy = ph ? W1b : W1a;
    #pragma unroll
    for (int ch = 0; ch < 2; ++ch) {
      __syncthreads();
      #pragma unroll
      for (int e = 0; e < 8; ++e) {
        int idx = t + e * 256;
        int o = idx >> 4, k4 = idx & 15;
        float4 wv = *(const float4*)(Wx + o * DD + ch * 64 + k4 * 4);
        uint2 pw; pw.x = pack2(wv.x, wv.y); pw.y = pack2(wv.z, wv.w);
        *(uint2*)&Wsm[0][o * 72 + k4 * 4] = pw;
        float4 wv2 = *(const float4*)(Wy + o * DD + ch * 64 + k4 * 4);
        uint2 pw2; pw2.x = pack2(wv2.x, wv2.y); pw2.y = pack2(wv2.z, wv2.w);
        *(uint2*)&Wsm[1][o * 72 + k4 * 4] = pw2;
      }
      __syncthreads();
      #pragma unroll
      for (int s = 0; s < 2; ++s) {
        int kx = ch * 64 + s * 32 + lq * 8;
        bf16x8 bfr = *(const bf16x8*)&Xt[jloc * 136 + kx];
        int kw = s * 32 + lq * 8;
        #pragma unroll
        for (int mt = 0; mt < 8; ++mt) {
          bf16x8 a0 = *(const bf16x8*)&Wsm[0][(mt * 16 + lm) * 72 + kw];
          acc0[mt] = __builtin_amdgcn_mfma_f32_16x16x32_bf16(a0, bfr, acc0[mt], 0, 0, 0);
          bf16x8 a1 = *(const bf16x8*)&Wsm[1][(mt * 16 + lm) * 72 + kw];
          acc1[mt] = __builtin_amdgcn_mfma_f32_16x16x32_bf16(a1, bfr, acc1[mt], 0, 0, 0);
        }
      }
    }
  }

  #pragma unroll
  for (int set = 0; set < 2; ++set) {
    __syncthreads();
    f32x4* acc = set ? acc1 : acc0;
    float psum = 0.f;
    float hv[8][4];
    #pragma unroll
    for (int mt = 0; mt < 8; ++mt)
      #pragma unroll
      for (int r = 0; r < 4; ++r) {
        int o = mt * 16 + lq * 4 + r;
        float v = fmaxf(acc[mt][r] + bsm[set][o], 0.f);
        hv[mt][r] = v;
        psum += v * v;
      }
    psum += __shfl_xor(psum, 16);
    psum += __shfl_xor(psum, 32);
    float rn = 1.f / (sqrtf(psum) + 1e-9f);
    #pragma unroll
    for (int mt = 0; mt < 8; ++mt)
      #pragma unroll
      for (int r = 0; r < 4; ++r) {
        int o = mt * 16 + lq * 4 + r;
        Ho[jloc * 132 + o] = hv[mt][r] * rn;
      }
    __syncthreads();
    __hip_bfloat16* ob = set ? out1 : out0;
    #pragma unroll
    for (int e = 0; e < 4; ++e) {
      int idx = t + e * 256;
      int r = idx >> 4, c8 = idx & 15;
      const float* h = &Ho[r * 132 + c8 * 8];
      unsigned pk[4] = {pack2(h[0], h[1]), pack2(h[2], h[3]),
                        pack2(h[4], h[5]), pack2(h[6], h[7])};
      *(uint4*)((unsigned short*)ob + (rowbase + r) * DD + c8 * 8) = *(uint4*)pk;
    }
  }
}

// Round-2 merged linred. z=0: assignment branch with FUSED softmax epilogue
// (emits Sbf row-major, STt transposed, per-block entropy). z=1: embedding
// branch, l2norm epilogue, transposed bf16 h2T out.
__global__ __launch_bounds__(256) void k_linz(const __hip_bfloat16* __restrict__ AG0,
                                              const __hip_bfloat16* __restrict__ X0,
                                              const float* __restrict__ W0a,
                                              const float* __restrict__ W0b,
                                              const float* __restrict__ b0,
                                              __hip_bfloat16* __restrict__ Sbf,
                                              __hip_bfloat16* __restrict__ STt,
                                              float* __restrict__ entpart,
                                              const __hip_bfloat16* __restrict__ AG1,
                                              const __hip_bfloat16* __restrict__ X1,
                                              const float* __restrict__ W1a,
                                              const float* __restrict__ W1b,
                                              const float* __restrict__ b1,
                                              __hip_bfloat16* __restrict__ out1T) {
  __shared__ __align__(16) char smem[64 * 136 * 2 * 2];
  __shared__ __align__(16) __hip_bfloat16 Wsm[128 * 72];
  __shared__ float bsm[128];
  __shared__ float entred[64];
  __hip_bfloat16* As = (__hip_bfloat16*)smem;
  __hip_bfloat16* Xs = As + 64 * 136;
  float* Ho = (float*)smem;

  int mode = blockIdx.z;
  const __hip_bfloat16* AGG = mode ? AG1 : AG0;
  const __hip_bfloat16* X2 = mode ? X1 : X0;
  const float* Wl = mode ? W1a : W0a;
  const float* Wr = mode ? W1b : W0b;
  const float* bias = mode ? b1 : b0;

  int b = blockIdx.y, j0 = blockIdx.x * 64;
  int t = threadIdx.x;
  size_t rowbase = (size_t)b * NN + j0;

  if (t < 128) bsm[t] = bias[t];
  #pragma unroll
  for (int e = 0; e < 8; ++e) {
    int idx = t + e * 256;
    int r = idx >> 5, c4 = idx & 31;
    size_t g = (rowbase + r) * DD + c4 * 4;
    *(uint2*)&As[r * 136 + c4 * 4] = *(const uint2*)((const unsigned short*)AGG + g);
    *(uint2*)&Xs[r * 136 + c4 * 4] = *(const uint2*)((const unsigned short*)X2 + g);
  }
  __syncthreads();

  int w = t >> 6, l = t & 63;
  int lm = l & 15, lq = l >> 4;
  int jloc = w * 16 + lm;
  f32x4 acc[8];
  #pragma unroll
  for (int mt = 0; mt < 8; ++mt)
    #pragma unroll
    for (int r = 0; r < 4; ++r) acc[mt][r] = 0.f;

  #pragma unroll
  for (int ph = 0; ph < 2; ++ph) {
    const __hip_bfloat16* Xt = ph ? Xs : As;
    const float* W = ph ? Wr : Wl;
    #pragma unroll
    for (int ch = 0; ch < 2; ++ch) {
      __syncthreads();
      #pragma unroll
      for (int e = 0; e < 8; ++e) {
        int idx = t + e * 256;
        int o = idx >> 4, k4 = idx & 15;
        float4 wv = *(const float4*)(W + o * DD + ch * 64 + k4 * 4);
        uint2 pw; pw.x = pack2(wv.x, wv.y); pw.y = pack2(wv.z, wv.w);
        *(uint2*)&Wsm[o * 72 + k4 * 4] = pw;
      }
      __syncthreads();
      #pragma unroll
      for (int s = 0; s < 2; ++s) {
        int kx = ch * 64 + s * 32 + lq * 8;
        bf16x8 bfr = *(const bf16x8*)&Xt[jloc * 136 + kx];
        int kw = s * 32 + lq * 8;
        #pragma unroll
        for (int mt = 0; mt < 8; ++mt) {
          bf16x8 afr = *(const bf16x8*)&Wsm[(mt * 16 + lm) * 72 + kw];
          acc[mt] = __builtin_amdgcn_mfma_f32_16x16x32_bf16(afr, bfr, acc[mt], 0, 0, 0);
        }
      }
    }
  }

  __syncthreads();
  float hv[8][4];
  float psum = 0.f;
  #pragma unroll
  for (int mt = 0; mt < 8; ++mt)
    #pragma unroll
    for (int r = 0; r < 4; ++r) {
      int o = mt * 16 + lq * 4 + r;
      float v = fmaxf(acc[mt][r] + bsm[o], 0.f);
      hv[mt][r] = v;
      psum += v * v;
    }
  psum += __shfl_xor(psum, 16);
  psum += __shfl_xor(psum, 32);
  float rn = 1.f / (sqrtf(psum) + 1e-9f);

  if (mode == 0) {
    float av[8][4];
    float m = -3.4e38f;
    #pragma unroll
    for (int mt = 0; mt < 8; ++mt)
      #pragma unroll
      for (int r = 0; r < 4; ++r) {
        float a = hv[mt][r] * rn;
        av[mt][r] = a;
        m = fmaxf(m, a);
      }
    m = fmaxf(m, __shfl_xor(m, 16));
    m = fmaxf(m, __shfl_xor(m, 32));
    float sum = 0.f;
    #pragma unroll
    for (int mt = 0; mt < 8; ++mt)
      #pragma unroll
      for (int r = 0; r < 4; ++r) {
        float e = expf(av[mt][r] - m);
        av[mt][r] = e;
        sum += e;
      }
    sum += __shfl_xor(sum, 16);
    sum += __shfl_xor(sum, 32);
    float inv = 1.f / sum;
    float ent = 0.f;
    #pragma unroll
    for (int mt = 0; mt < 8; ++mt)
      #pragma unroll
      for (int r = 0; r < 4; ++r) {
        float p = av[mt][r] * inv;
        ent -= p * logf(p + 1e-15f);
        int o = mt * 16 + lq * 4 + r;
        Ho[jloc * 132 + o] = p;
      }
    ent += __shfl_xor(ent, 16);
    ent += __shfl_xor(ent, 32);
    if (l < 16) entred[w * 16 + lm] = ent;
    __syncthreads();
    #pragma unroll
    for (int e = 0; e < 4; ++e) {
      int idx = t + e * 256;
      int r = idx >> 4, c8 = idx & 15;
      const float* h = &Ho[r * 132 + c8 * 8];
      unsigned pk[4] = {pack2(h[0], h[1]), pack2(h[2], h[3]),
                        pack2(h[4], h[5]), pack2(h[6], h[7])};
      *(uint4*)((unsigned short*)Sbf + (rowbase + r) * DD + c8 * 8) = *(uint4*)pk;
    }
    {
      int d = t >> 1, half = t & 1;
      unsigned wv[16];
      #pragma unroll
      for (int e = 0; e < 16; ++e)
        wv[e] = pack2(Ho[(half * 32 + 2 * e) * 132 + d], Ho[(half * 32 + 2 * e + 1) * 132 + d]);
      unsigned short* dst = (unsigned short*)STt + ((size_t)b * DD + d) * NN + j0 + half * 32;
      #pragma unroll
      for (int q = 0; q < 4; ++q)
        *(uint4*)(dst + q * 8) = *(uint4*)&wv[q * 4];
    }
    if (t < 64) {
      float s = entred[t];
      #pragma unroll
      for (int off = 32; off > 0; off >>= 1) s += __shfl_xor(s, off);
      if (t == 0) entpart[blockIdx.y * 32 + blockIdx.x] = s;
    }
  } else {
    #pragma unroll
    for (int mt = 0; mt < 8; ++mt)
      #pragma unroll
      for (int r = 0; r < 4; ++r) {
        int o = mt * 16 + lq * 4 + r;
        Ho[jloc * 132 + o] = hv[mt][r] * rn;
      }
    __syncthreads();
    int d = t >> 1, half = t & 1;
    unsigned wv[16];
    #pragma unroll
    for (int e = 0; e < 16; ++e)
      wv[e] = pack2(Ho[(half * 32 + 2 * e) * 132 + d], Ho[(half * 32 + 2 * e + 1) * 132 + d]);
    unsigned short* dst = (unsigned short*)out1T + ((size_t)b * DD + d) * NN + j0 + half * 32;
    #pragma unroll
    for (int q = 0; q < 4; ++q)
      *(uint4*)(dst + q * 8) = *(uint4*)&wv[q * 4];
  }
}

// TN MFMA: pair0 ST·h2T^T (h_pooled), pair1 PT·ST^T (adj_pooled), pair2 ST·ST^T (G)
__global__ __launch_bounds__(256) void k_tnm(const __hip_bfloat16* __restrict__ ST,
                                             const __hip_bfloat16* __restrict__ HT,
                                             const __hip_bfloat16* __restrict__ PT,
                                             float* __restrict__ part) {
  __shared__ __align__(16) __hip_bfloat16 As[128 * 64];
  __shared__ __align__(16) __hip_bfloat16 Bs[128 * 64];
  int pb = blockIdx.y;
  int pair = pb >> 3, b = pb & 7;
  const __hip_bfloat16* Xa = (pair == 1) ? PT : ST;
  const __hip_bfloat16* Ya = (pair == 0) ? HT : ST;
  const __hip_bfloat16* Ab = Xa + (size_t)b * DD * NN;
  const __hip_bfloat16* Bb = Ya + (size_t)b * DD * NN;
  int k0 = blockIdx.x * (NN / SPL);
  int tid = threadIdx.x;
  int w = tid >> 6, l = tid & 63;
  int wj = w & 1, wd = w >> 1;
  int sr = l >> 3, ss = l & 7;
  int lm = l & 15, lq = l >> 4;
  f32x4 acc[4][4];
  #pragma unroll
  for (int a = 0; a < 4; ++a)
    #pragma unroll
    for (int c = 0; c < 4; ++c)
      #pragma unroll
      for (int r = 0; r < 4; ++r) acc[a][c][r] = 0.f;

  for (int kb = 0; kb < (NN / SPL) / 64; ++kb) {
    int kbase = k0 + kb * 64;
    __syncthreads();
    #pragma unroll
    for (int e = 0; e < 4; ++e) {
      int r = 32 * w + 8 * e + sr;
      int g = ss ^ (r & 7);
      const __hip_bfloat16* srcA = Ab + (size_t)r * NN + kbase + g * 8;
      __builtin_amdgcn_global_load_lds(
          (const __attribute__((address_space(1))) void*)srcA,
          (__attribute__((address_space(3))) void*)&As[(32 * w + 8 * e) * 64], 16, 0, 0);
      const __hip_bfloat16* srcB = Bb + (size_t)r * NN + kbase + g * 8;
      __builtin_amdgcn_global_load_lds(
          (const __attribute__((address_space(1))) void*)srcB,
          (__attribute__((address_space(3))) void*)&Bs[(32 * w + 8 * e) * 64], 16, 0, 0);
    }
    __syncthreads();
    #pragma unroll
    for (int ks = 0; ks < 2; ++ks) {
      bf16x8 afr[4], bfr[4];
      int kg = ks * 4 + lq;
      #pragma unroll
      for (int jt = 0; jt < 4; ++jt) {
        int jl = wj * 64 + jt * 16 + lm;
        afr[jt] = *(const bf16x8*)&As[jl * 64 + ((kg ^ (jl & 7)) << 3)];
      }
      #pragma unroll
      for (int dt = 0; dt < 4; ++dt) {
        int dl = wd * 64 + dt * 16 + lm;
        bfr[dt] = *(const bf16x8*)&Bs[dl * 64 + ((kg ^ (dl & 7)) << 3)];
      }
      #pragma unroll
      for (int jt = 0; jt < 4; ++jt)
        #pragma unroll
        for (int dt = 0; dt < 4; ++dt)
          acc[jt][dt] = __builtin_amdgcn_mfma_f32_16x16x32_bf16(afr[jt], bfr[dt], acc[jt][dt], 0, 0, 0);
    }
  }
  float* P = part + ((size_t)(pair * SPL + blockIdx.x) * BB + b) * DD * DD;
  #pragma unroll
  for (int jt = 0; jt < 4; ++jt)
    #pragma unroll
    for (int reg = 0; reg < 4; ++reg) {
      int j = wj * 64 + jt * 16 + lq * 4 + reg;
      float* row = P + (size_t)j * DD;
      #pragma unroll
      for (int dt = 0; dt < 4; ++dt)
        row[wd * 64 + dt * 16 + lm] = acc[jt][dt][reg];
    }
}

// reduce SPL partials; per-block trace/sumsq partials (no atomics, no fences)
__global__ __launch_bounds__(256) void k_tnred3(const float* __restrict__ part,
                                                float* __restrict__ out,
                                                float* __restrict__ trpart,
                                                float* __restrict__ sqpart) {
  __shared__ float red[256];
  int pair = blockIdx.y;
  size_t i = (size_t)blockIdx.x * 256 + threadIdx.x;     // < B*D*D = 131072
  float s = 0.f;
  #pragma unroll
  for (int ks = 0; ks < SPL; ++ks)
    s += part[((size_t)pair * SPL + ks) * (BB * DD * DD) + i];
  float contrib = 0.f;
  if (pair == 0) {
    out[i] = s;
  } else if (pair == 1) {
    out[(size_t)BB * DD * DD + i] = s;
    int rc = (int)(i & (DD * DD - 1));
    if ((rc >> 7) == (rc & 127)) contrib = s;
  } else {
    contrib = s * s;
  }
  red[threadIdx.x] = contrib;
  __syncthreads();
  for (int off = 128; off > 0; off >>= 1) {
    if (threadIdx.x < off) red[threadIdx.x] += red[threadIdx.x + off];
    __syncthreads();
  }
  if (threadIdx.x == 0) {
    if (pair == 1) trpart[blockIdx.x] = red[0];
    else if (pair == 2) sqpart[blockIdx.x] = red[0];
  }
}

__global__ __launch_bounds__(256) void k_final(const float* __restrict__ nnzpart,
                                               const float* __restrict__ entpart,
                                               const float* __restrict__ trpart,
                                               const float* __restrict__ sqpart,
                                               float* __restrict__ out) {
  __shared__ float4 red[256];
  int t = threadIdx.x;
  float4 v;
  v.x = nnzpart[t] + nnzpart[t + 256];
  v.y = entpart[t];
  v.z = trpart[t] + trpart[t + 256];
  v.w = sqpart[t] + sqpart[t + 256];
  red[t] = v;
  __syncthreads();
  for (int off = 128; off > 0; off >>= 1) {
    if (t < off) {
      red[t].x += red[t + off].x; red[t].y += red[t + off].y;
      red[t].z += red[t + off].z; red[t].w += red[t + off].w;
    }
    __syncthreads();
  }
  if (t == 0) {
    double link2 = (double)red[0].x - 2.0 * (double)red[0].z + (double)red[0].w;
    if (link2 < 0.0) link2 = 0.0;
    out[2 * BB * DD * DD]     = (float)(sqrt(link2) / (double)((size_t)BB * NN * NN));
    out[2 * BB * DD * DD + 1] = (float)((double)red[0].y / (double)(BB * NN));
  }
}

extern "C" void kernel_launch(void* const* d_in, const int* in_sizes, int n_in,
                              void* d_out, int out_size, void* d_ws, size_t ws_size,
                              hipStream_t stream) {
  const float* x    = (const float*)d_in[0];
  const float* adj  = (const float*)d_in[1];
  const float* We1l = (const float*)d_in[2];
  const float* be1  = (const float*)d_in[3];
  const float* We1r = (const float*)d_in[4];
  const float* We2l = (const float*)d_in[5];
  const float* be2  = (const float*)d_in[6];
  const float* We2r = (const float*)d_in[7];
  const float* Wa1l = (const float*)d_in[8];
  const float* ba1  = (const float*)d_in[9];
  const float* Wa1r = (const float*)d_in[10];
  const float* Wa2l = (const float*)d_in[11];
  const float* ba2  = (const float*)d_in[12];
  const float* Wa2r = (const float*)d_in[13];
  float* out = (float*)d_out;

  const size_t MB = 1 << 20;
  char* ws = (char*)d_ws;
  float* nnzpart = (float*)(ws);                           // 512 f
  float* entpart = (float*)(ws + 4096);                    // 256 f
  float* trpart  = (float*)(ws + 8192);                    // 512 f
  float* sqpart  = (float*)(ws + 12288);                   // 512 f
  float* cnth    = (float*)(ws + 16384);                   // 128 KiB
  unsigned short* colidx = (unsigned short*)(ws + 1 * MB); // 2 MiB
  __hip_bfloat16* xbf   = (__hip_bfloat16*)(ws + 3 * MB);  // 4 MiB
  __hip_bfloat16* agg1  = (__hip_bfloat16*)(ws + 7 * MB);  // 4 MiB (also agg2a)
  __hip_bfloat16* agg2h = (__hip_bfloat16*)(ws + 11 * MB); // 4 MiB
  __hip_bfloat16* a1bf  = (__hip_bfloat16*)(ws + 15 * MB); // 4 MiB
  __hip_bfloat16* h1bf  = (__hip_bfloat16*)(ws + 19 * MB); // 4 MiB
  __hip_bfloat16* Sbf   = (__hip_bfloat16*)(ws + 23 * MB); // 4 MiB
  __hip_bfloat16* STt   = (__hip_bfloat16*)(ws + 27 * MB); // 4 MiB
  __hip_bfloat16* h2T   = (__hip_bfloat16*)(ws + 31 * MB); // 4 MiB
  __hip_bfloat16* PT    = (__hip_bfloat16*)(ws + 35 * MB); // 4 MiB
  float* part           = (float*)(ws + 39 * MB);          // 12.6 MiB

  dim3 gb(32, 8, 2), glr(32, 8), glz(32, 8, 2), gtm(SPL, 24), gtr(512, 3);

  k_build<<<gb, 256, 0, stream>>>(adj, x, colidx, cnth, nnzpart, xbf);
  // round 1: shared mean-aggregation of x (high-TLP), dual linred (h1, a1)
  k_agg<<<4096, 256, 0, stream>>>(xbf, colidx, cnth, agg1);
  k_lin2<<<glr, 256, 0, stream>>>(agg1, xbf, We1l, We1r, be1, Wa1l, Wa1r, ba1, h1bf, a1bf);
  // round 2: batched aggregation of (a1, h1); merged linreds (a2+softmax, h2T)
  k_agg2<<<4096, 256, 0, stream>>>(a1bf, h1bf, colidx, cnth, agg1, agg2h);
  k_linz<<<glz, 256, 0, stream>>>(agg1, a1bf, Wa2l, Wa2r, ba2, Sbf, STt, entpart,
                                  agg2h, h1bf, We2l, We2r, be2, h2T);
  // P = A^T S, transposed emission
  k_aggT<<<1024, 256, 0, stream>>>(Sbf, colidx, cnth, PT);
  // pooled outputs + scalar reductions
  k_tnm<<<gtm, 256, 0, stream>>>(STt, h2T, PT, part);
  k_tnred3<<<gtr, 256, 0, stream>>>(part, out, trpart, sqpart);
  k_final<<<1, 256, 0, stream>>>(nnzpart, entpart, trpart, sqpart, out);
}